// Round 4
// baseline (595.251 us; speedup 1.0000x reference)
//
#include <hip/hip_runtime.h>
#include <math.h>

// Problem constants: B=4, S=1024, D=512, H=8, HD=64, HID=2048
#define kB 4
#define kS 1024
#define kD 512
#define kH 8
#define kHD 64
#define kHID 2048
#define kNT (kB * kS)          // 4096 tokens
#define kBSD (kNT * kD)        // 2,097,152
#define kDD (kD * kD)          // 262,144
#define kDH (kHID * kD)        // 1,048,576

typedef __attribute__((ext_vector_type(8))) short bf16x8;
typedef __attribute__((ext_vector_type(4))) float f32x4;

#define AS1 __attribute__((address_space(1)))
#define AS3 __attribute__((address_space(3)))

__device__ __forceinline__ float bf2f(unsigned short u) {
  return __uint_as_float(((unsigned int)u) << 16);
}
__device__ __forceinline__ unsigned short f2bf(float f) {
  unsigned int u = __float_as_uint(f);
  u += 0x7fffu + ((u >> 16) & 1u);   // RNE
  return (unsigned short)(u >> 16);
}

// ---------------------------------------------------------------------------
// Standard cat-weight build (O, gate, up, down): complex W (M,K) ->
// (2M x 2K) real block, rows [wr|-wi] then [wi|wr].
// ---------------------------------------------------------------------------
__global__ __launch_bounds__(256) void build_wcat_kernel(
    const float* __restrict__ lm, const float* __restrict__ ph,
    unsigned short* __restrict__ dst, int M, int K, int kshift) {
  int id = blockIdx.x * 256 + threadIdx.x;
  if (id >= M * K) return;
  int m = id >> kshift, k = id & (K - 1);
  float mm = __expf(lm[id]);
  float s, c;
  __sincosf(ph[id], &s, &c);
  float wr = mm * c, wi = mm * s;
  size_t ld = 2 * (size_t)K;
  dst[(size_t)m * ld + k] = f2bf(wr);
  dst[(size_t)m * ld + K + k] = f2bf(-wi);
  dst[(size_t)(M + m) * ld + k] = f2bf(wi);
  dst[(size_t)(M + m) * ld + K + k] = f2bf(wr);
}

// ---------------------------------------------------------------------------
// Head-permuted QKV weight build: output col = blk*1024 + h*128 + ri*64 + d
// for complex feature m = h*64+d of matrix blk (0=q,1=k,2=v). ld = 1024.
// ---------------------------------------------------------------------------
__global__ __launch_bounds__(256) void build_wcat_perm_kernel(
    const float* __restrict__ lm, const float* __restrict__ ph,
    unsigned short* __restrict__ dst, int blk) {
  int id = blockIdx.x * 256 + threadIdx.x;  // m*512 + k
  if (id >= 512 * 512) return;
  int m = id >> 9, k = id & 511;
  float mm = __expf(lm[id]);
  float s, c;
  __sincosf(ph[id], &s, &c);
  float wr = mm * c, wi = mm * s;
  int h = m >> 6, d = m & 63;
  size_t rowR = (size_t)blk * 1024 + h * 128 + d;
  size_t rowI = rowR + 64;
  dst[rowR * 1024 + k] = f2bf(wr);
  dst[rowR * 1024 + 512 + k] = f2bf(-wi);
  dst[rowI * 1024 + k] = f2bf(wi);
  dst[rowI * 1024 + 512 + k] = f2bf(wr);
}

// standard bias: dst[m] = bm*cos(bp), dst[M+m] = bm*sin(bp)
__global__ __launch_bounds__(256) void build_bias_kernel(
    const float* __restrict__ bm, const float* __restrict__ bp,
    float* __restrict__ dst, int M) {
  int m = blockIdx.x * 256 + threadIdx.x;
  if (m < M) {
    float s, c;
    __sincosf(bp[m], &s, &c);
    dst[m] = bm[m] * c;
    dst[M + m] = bm[m] * s;
  }
}

// head-permuted bias for QKV
__global__ __launch_bounds__(256) void build_bias_perm_kernel(
    const float* __restrict__ bm, const float* __restrict__ bp,
    float* __restrict__ dst, int blk) {
  int m = blockIdx.x * 256 + threadIdx.x;
  if (m < 512) {
    float s, c;
    __sincosf(bp[m], &s, &c);
    int h = m >> 6, d = m & 63;
    dst[blk * 1024 + h * 128 + d] = bm[m] * c;
    dst[blk * 1024 + h * 128 + 64 + d] = bm[m] * s;
  }
}

// ---------------------------------------------------------------------------
// Complex LayerNorm: one WAVE per token, shfl butterflies, no barriers.
// fp32 in (row stride `stride`) -> bf16 (N,1024) [r|i] out. grid = NT/4.
// ---------------------------------------------------------------------------
__global__ __launch_bounds__(256) void cln_kernel(
    const float* __restrict__ xr, const float* __restrict__ xi, int stride,
    const float* __restrict__ g_r, const float* __restrict__ g_i,
    const float* __restrict__ b_r, const float* __restrict__ b_i,
    unsigned short* __restrict__ out) {
  int w = threadIdx.x >> 6, lane = threadIdx.x & 63;
  int t = blockIdx.x * 4 + w;
  int d0 = lane * 8;
  const float* xrt = xr + (size_t)t * stride + d0;
  const float* xit = xi + (size_t)t * stride + d0;
  float4 a0 = *(const float4*)&xrt[0];
  float4 a1 = *(const float4*)&xrt[4];
  float4 c0 = *(const float4*)&xit[0];
  float4 c1 = *(const float4*)&xit[4];

  float s1 = a0.x + a0.y + a0.z + a0.w + a1.x + a1.y + a1.z + a1.w;
  float s2 = c0.x + c0.y + c0.z + c0.w + c1.x + c1.y + c1.z + c1.w;
#pragma unroll
  for (int off = 1; off < 64; off <<= 1) {
    s1 += __shfl_xor(s1, off);
    s2 += __shfl_xor(s2, off);
  }
  float mr = s1 * (1.f / kD), mi = s2 * (1.f / kD);

  float ar[8] = {a0.x, a0.y, a0.z, a0.w, a1.x, a1.y, a1.z, a1.w};
  float ai[8] = {c0.x, c0.y, c0.z, c0.w, c1.x, c1.y, c1.z, c1.w};
  float v = 0.f;
#pragma unroll
  for (int e = 0; e < 8; e++) {
    float cr = ar[e] - mr, ci = ai[e] - mi;
    v += cr * cr + ci * ci;
  }
#pragma unroll
  for (int off = 1; off < 64; off <<= 1) v += __shfl_xor(v, off);
  float inv = rsqrtf(v * (1.f / kD) + 1e-6f);

  float4 g0 = *(const float4*)&g_r[d0];
  float4 g1 = *(const float4*)&g_r[d0 + 4];
  float4 h0 = *(const float4*)&g_i[d0];
  float4 h1 = *(const float4*)&g_i[d0 + 4];
  float4 p0 = *(const float4*)&b_r[d0];
  float4 p1 = *(const float4*)&b_r[d0 + 4];
  float4 q0 = *(const float4*)&b_i[d0];
  float4 q1 = *(const float4*)&b_i[d0 + 4];
  float gr[8] = {g0.x, g0.y, g0.z, g0.w, g1.x, g1.y, g1.z, g1.w};
  float gi[8] = {h0.x, h0.y, h0.z, h0.w, h1.x, h1.y, h1.z, h1.w};
  float br[8] = {p0.x, p0.y, p0.z, p0.w, p1.x, p1.y, p1.z, p1.w};
  float bi[8] = {q0.x, q0.y, q0.z, q0.w, q1.x, q1.y, q1.z, q1.w};

  unsigned short pr[8], pi[8];
#pragma unroll
  for (int e = 0; e < 8; e++) {
    float nr = (ar[e] - mr) * inv;
    float ni = (ai[e] - mi) * inv;
    pr[e] = f2bf(nr * gr[e] - ni * gi[e] + br[e]);
    pi[e] = f2bf(nr * gi[e] + ni * gr[e] + bi[e]);
  }
  unsigned short* ot = out + (size_t)t * 1024 + d0;
  *(bf16x8*)&ot[0] = *(const bf16x8*)pr;
  *(bf16x8*)&ot[512] = *(const bf16x8*)pi;
}

// ---------------------------------------------------------------------------
// bf16 MFMA GEMM (m97 structure + XOR-swizzled LDS + staged epilogue).
// out[n][m] = sum_k X[n][k]*W[m][k]. 128x128 tile, BK=32, 4 waves.
// Swizzle: staging lane for slot (r, g) loads global granule g^(r&3);
// ds_read uses granule quad^(l15&3) -> conflict-free (2-way max).
// Epilogue modes:
//   0: out bf16 (N,ldo) += bias, LDS-staged coalesced stores
//   1: O-proj: outf fp32 (N,1024) = acc + bias + x residual
//   2: down:   d_out fp32 split halves = acc + resr[row*1024+col]
//   3: QKV:    q/k blocks like mode 0; V blocks (col>=2048) direct
//              transposed ushort4 stores to vt[b][h][dcat][s]
// ---------------------------------------------------------------------------
__global__ __launch_bounds__(256) void cgemm_mfma_kernel(
    const unsigned short* __restrict__ X, int ldx,
    const unsigned short* __restrict__ Wt, int K,
    const float* __restrict__ bias, int mode,
    const float* __restrict__ resr, const float* __restrict__ resi,
    unsigned short* __restrict__ outb, int ldo,
    float* __restrict__ outf, unsigned short* __restrict__ vtb) {
  __shared__ unsigned short Sh[128 * 132];  // 33 KB; head doubles as staging
  unsigned short* Xs = Sh;                  // 128*32 shorts
  unsigned short* Ws = Sh + 4096;           // 128*32 shorts

  const int tid = threadIdx.x;
  const int w = tid >> 6;
  const int lane = tid & 63;
  const int quad = lane >> 4;
  const int l15 = lane & 15;
  const int m0 = blockIdx.x * 128;
  const int n0 = blockIdx.y * 128;
  const int wm = (w & 1) * 64;
  const int wn = (w >> 1) * 64;

  const int idx0 = w * 128 + lane;
  const int idx1 = idx0 + 64;
  const int r0 = idx0 >> 2, c0 = (((idx0 & 3) ^ (r0 & 3))) * 8;  // swizzled
  const int r1 = idx1 >> 2, c1 = (((idx1 & 3) ^ (r1 & 3))) * 8;
  const unsigned short* gx0 = X + (size_t)(n0 + r0) * ldx + c0;
  const unsigned short* gx1 = X + (size_t)(n0 + r1) * ldx + c1;
  const unsigned short* gw0 = Wt + (size_t)(m0 + r0) * K + c0;
  const unsigned short* gw1 = Wt + (size_t)(m0 + r1) * K + c1;
  unsigned short* lx0 = &Xs[(w * 2 + 0) * 512];
  unsigned short* lx1 = &Xs[(w * 2 + 1) * 512];
  unsigned short* lw0 = &Ws[(w * 2 + 0) * 512];
  unsigned short* lw1 = &Ws[(w * 2 + 1) * 512];

  const int sg = (quad ^ (l15 & 3)) * 8;    // swizzled read granule

  f32x4 acc[4][4];
#pragma unroll
  for (int i = 0; i < 4; i++)
#pragma unroll
    for (int j = 0; j < 4; j++) acc[i][j] = (f32x4){0.f, 0.f, 0.f, 0.f};

  for (int k0 = 0; k0 < K; k0 += 32) {
    __syncthreads();
    __builtin_amdgcn_global_load_lds((const AS1 void*)(gx0 + k0), (AS3 void*)lx0, 16, 0, 0);
    __builtin_amdgcn_global_load_lds((const AS1 void*)(gx1 + k0), (AS3 void*)lx1, 16, 0, 0);
    __builtin_amdgcn_global_load_lds((const AS1 void*)(gw0 + k0), (AS3 void*)lw0, 16, 0, 0);
    __builtin_amdgcn_global_load_lds((const AS1 void*)(gw1 + k0), (AS3 void*)lw1, 16, 0, 0);
    __syncthreads();

    bf16x8 af[4], bf[4];
#pragma unroll
    for (int t = 0; t < 4; t++) {
      af[t] = *(const bf16x8*)&Xs[(wn + t * 16 + l15) * 32 + sg];
      bf[t] = *(const bf16x8*)&Ws[(wm + t * 16 + l15) * 32 + sg];
    }
#pragma unroll
    for (int i = 0; i < 4; i++)
#pragma unroll
      for (int j = 0; j < 4; j++)
        acc[i][j] = __builtin_amdgcn_mfma_f32_16x16x32_bf16(af[i], bf[j], acc[i][j], 0, 0, 0);
  }

  // ---- epilogue; D mapping: col=lane&15 (feature), row=(lane>>4)*4+reg ----
  if (mode == 0 || (mode == 3 && m0 < 2048)) {
    // LDS-staged coalesced bf16 output
    __syncthreads();
#pragma unroll
    for (int j = 0; j < 4; ++j) {
      int colL = wm + j * 16 + l15;
      float bv = bias ? bias[m0 + colL] : 0.f;
#pragma unroll
      for (int i = 0; i < 4; ++i) {
        int rowL = wn + i * 16 + quad * 4;
#pragma unroll
        for (int r = 0; r < 4; ++r)
          Sh[(rowL + r) * 132 + colL] = f2bf(acc[i][j][r] + bv);
      }
    }
    __syncthreads();
    int row = tid >> 1, hc = (tid & 1) * 64;
    const unsigned short* src = &Sh[row * 132 + hc];
    unsigned short* dst = &outb[(size_t)(n0 + row) * ldo + m0 + hc];
#pragma unroll
    for (int u = 0; u < 8; u++)
      *(bf16x8*)(dst + u * 8) = *(const bf16x8*)(src + u * 8);
  } else if (mode == 3) {
    // V blocks: direct transposed stores vt[b][h][dcat][s]
#pragma unroll
    for (int j = 0; j < 4; ++j) {
      int col = m0 + wm + j * 16 + l15;
      float bv = bias ? bias[col] : 0.f;
      int hh = (col - 2048) >> 7, dcat = (col - 2048) & 127;
#pragma unroll
      for (int i = 0; i < 4; ++i) {
        int row0 = n0 + wn + i * 16 + quad * 4;
        int bb = row0 >> 10, s0 = row0 & 1023;
        ushort4 pk;
        pk.x = f2bf(acc[i][j][0] + bv);
        pk.y = f2bf(acc[i][j][1] + bv);
        pk.z = f2bf(acc[i][j][2] + bv);
        pk.w = f2bf(acc[i][j][3] + bv);
        *(ushort4*)&vtb[(size_t)((bb * 8 + hh) * 128 + dcat) * 1024 + s0] = pk;
      }
    }
  } else {
    // fp32 outputs with residual
#pragma unroll
    for (int j = 0; j < 4; ++j) {
      int col = m0 + wm + j * 16 + l15;
      float bv = bias ? bias[col] : 0.f;
#pragma unroll
      for (int i = 0; i < 4; ++i) {
        int row0 = n0 + wn + i * 16 + quad * 4;
#pragma unroll
        for (int r = 0; r < 4; ++r) {
          int row = row0 + r;
          float val = acc[i][j][r] + bv;
          if (mode == 1) {
            float xres = (col < 512) ? resr[(size_t)row * 512 + col]
                                     : resi[(size_t)row * 512 + col - 512];
            outf[(size_t)row * 1024 + col] = val + xres;
          } else {
            float rv = resr[(size_t)row * 1024 + col] + val;
            size_t d = (col < 512) ? ((size_t)row * 512 + col)
                                   : ((size_t)kBSD + (size_t)row * 512 + (col - 512));
            outf[d] = rv;
          }
        }
      }
    }
  }
}

// ---------------------------------------------------------------------------
// RoPE in place on qkv (N,3072), head-permuted layout:
// q at col h*128+ri*64+d, k at 1024+h*128+ri*64+d. Pairs (i, i+32), i<32.
// ---------------------------------------------------------------------------
__global__ __launch_bounds__(256) void rope_kernel(unsigned short* __restrict__ qkv) {
  int idx = blockIdx.x * 256 + threadIdx.x;  // 0 .. 4096*8*32-1
  int i = idx & 31;
  int h = (idx >> 5) & 7;
  int tok = idx >> 8;
  int s = tok & (kS - 1);
  float inv = __expf(-(float)i * (9.210340371976184f / 32.0f));
  float f = (float)s * inv;
  float sn, cs;
  __sincosf(f, &sn, &cs);
  size_t base0 = (size_t)tok * 3072 + h * 128 + i;
  const int offs[4] = {0, 64, 1024, 1088};  // qr, qi, kr, ki
#pragma unroll
  for (int comp = 0; comp < 4; comp++) {
    size_t base = base0 + offs[comp];
    float x0 = bf2f(qkv[base]), x1 = bf2f(qkv[base + 32]);
    qkv[base] = f2bf(x0 * cs - x1 * sn);
    qkv[base + 32] = f2bf(x1 * cs + x0 * sn);
  }
}

// ---------------------------------------------------------------------------
// MFMA flash attention (causal, Hermitian). Block = (b,h,64-query tile),
// 4 waves x 16 q-rows. K-tile = 32 keys. Scores: K=128 cat (qr|qi).(kr|ki).
// LDS: Ks 32x136 + Vs 128x40 + Ps 4x16x40 = 24,064 B.
// ---------------------------------------------------------------------------
__global__ __launch_bounds__(256) void attn_mfma_kernel(
    const unsigned short* __restrict__ qkv,   // (4096, 3072)
    const unsigned short* __restrict__ vt,    // (4,8,128,1024)
    unsigned short* __restrict__ out) {       // (4096, 1024) [ar|ai]
  __shared__ unsigned short Ks[32 * 136];
  __shared__ unsigned short Vs[128 * 40];
  __shared__ unsigned short Ps[4 * 16 * 40];

  const int tid = threadIdx.x;
  const int w = tid >> 6;
  const int lane = tid & 63;
  const int quad = lane >> 4;
  const int l15 = lane & 15;

  int bid = blockIdx.x;
  int qt = bid & 15;
  if ((bid >> 4) & 1) qt = 15 - qt;   // alternate heavy/light for balance
  const int h = (bid >> 4) & 7;
  const int b = bid >> 7;
  const int q0 = qt * 64;
  const int wrow0 = q0 + w * 16;      // wave's first query position

  bf16x8 qa[4];
  {
    size_t base = (size_t)(b * kS + wrow0 + l15) * 3072 + h * 128;
#pragma unroll
    for (int ks = 0; ks < 4; ks++)
      qa[ks] = *(const bf16x8*)&qkv[base + ks * 32 + quad * 8];
  }

  f32x4 oacc[8];
#pragma unroll
  for (int dt = 0; dt < 8; dt++) oacc[dt] = (f32x4){0.f, 0.f, 0.f, 0.f};
  float m_r[4] = {-1e30f, -1e30f, -1e30f, -1e30f};
  float l_r[4] = {0.f, 0.f, 0.f, 0.f};

  const int ktmax_blk = (q0 + 63) >> 5;
  const int ktmax_wav = (wrow0 + 15) >> 5;
  const float cexp = 0.1803368801f;  // (1/sqrt(64)) * log2(e)

  const unsigned short* gkbase = qkv + 1024 + h * 128;
  const unsigned short* gvbase = vt + (size_t)((b * 8 + h) * 128) * 1024;

  for (int kt = 0; kt <= ktmax_blk; ++kt) {
    const int k0 = kt * 32;
    __syncthreads();
    {
      int ch = tid * 2;
      int r = ch >> 4, cc = (ch & 15) * 8;
      const unsigned short* gk = gkbase + (size_t)(b * kS + k0) * 3072;
      *(bf16x8*)&Ks[r * 136 + cc] = *(const bf16x8*)&gk[(size_t)r * 3072 + cc];
      int r2 = (ch + 1) >> 4, cc2 = ((ch + 1) & 15) * 8;
      *(bf16x8*)&Ks[r2 * 136 + cc2] = *(const bf16x8*)&gk[(size_t)r2 * 3072 + cc2];
      int vr = ch >> 2, vc = (ch & 3) * 8;
      *(bf16x8*)&Vs[vr * 40 + vc] = *(const bf16x8*)&gvbase[(size_t)vr * 1024 + k0 + vc];
      int vr2 = (ch + 1) >> 2, vc2 = ((ch + 1) & 3) * 8;
      *(bf16x8*)&Vs[vr2 * 40 + vc2] = *(const bf16x8*)&gvbase[(size_t)vr2 * 1024 + k0 + vc2];
    }
    __syncthreads();

    if (kt <= ktmax_wav) {
      f32x4 s[2];
      s[0] = (f32x4){0.f, 0.f, 0.f, 0.f};
      s[1] = (f32x4){0.f, 0.f, 0.f, 0.f};
#pragma unroll
      for (int ns = 0; ns < 2; ns++)
#pragma unroll
        for (int ks = 0; ks < 4; ks++) {
          bf16x8 kb = *(const bf16x8*)&Ks[(ns * 16 + l15) * 136 + ks * 32 + quad * 8];
          s[ns] = __builtin_amdgcn_mfma_f32_16x16x32_bf16(qa[ks], kb, s[ns], 0, 0, 0);
        }

      if (k0 + 31 > wrow0) {
#pragma unroll
        for (int r = 0; r < 4; r++) {
          int qrow = wrow0 + quad * 4 + r;
          if (k0 + l15 > qrow) s[0][r] = -1e30f;
          if (k0 + 16 + l15 > qrow) s[1][r] = -1e30f;
        }
      }

      float alpha[4];
#pragma unroll
      for (int r = 0; r < 4; r++) {
        float mx = fmaxf(s[0][r], s[1][r]);
        mx = fmaxf(mx, __shfl_xor(mx, 1));
        mx = fmaxf(mx, __shfl_xor(mx, 2));
        mx = fmaxf(mx, __shfl_xor(mx, 4));
        mx = fmaxf(mx, __shfl_xor(mx, 8));
        float mn = fmaxf(m_r[r], mx);
        float al = exp2f((m_r[r] - mn) * cexp);
        m_r[r] = mn;
        float p0 = exp2f((s[0][r] - mn) * cexp);
        float p1 = exp2f((s[1][r] - mn) * cexp);
        s[0][r] = p0;
        s[1][r] = p1;
        float rs = p0 + p1;
        rs += __shfl_xor(rs, 1);
        rs += __shfl_xor(rs, 2);
        rs += __shfl_xor(rs, 4);
        rs += __shfl_xor(rs, 8);
        l_r[r] = l_r[r] * al + rs;
        alpha[r] = al;
      }

#pragma unroll
      for (int dt = 0; dt < 8; dt++)
#pragma unroll
        for (int r = 0; r < 4; r++) oacc[dt][r] *= alpha[r];

      unsigned short* pw = &Ps[w * 640];
#pragma unroll
      for (int r = 0; r < 4; r++) {
        int q = quad * 4 + r;
        pw[q * 40 + l15] = f2bf(s[0][r]);
        pw[q * 40 + 16 + l15] = f2bf(s[1][r]);
      }
      bf16x8 pa = *(const bf16x8*)&pw[l15 * 40 + quad * 8];

#pragma unroll
      for (int dt = 0; dt < 8; dt++) {
        bf16x8 vb = *(const bf16x8*)&Vs[(dt * 16 + l15) * 40 + quad * 8];
        oacc[dt] = __builtin_amdgcn_mfma_f32_16x16x32_bf16(pa, vb, oacc[dt], 0, 0, 0);
      }
    }
  }

  float inv[4];
#pragma unroll
  for (int r = 0; r < 4; r++) inv[r] = 1.f / l_r[r];
#pragma unroll
  for (int dt = 0; dt < 8; dt++) {
    int dcat = dt * 16 + l15;
    int col = (dcat < 64) ? (h * 64 + dcat) : (512 + h * 64 + dcat - 64);
#pragma unroll
    for (int r = 0; r < 4; r++) {
      int tok = b * kS + wrow0 + quad * 4 + r;
      out[(size_t)tok * 1024 + col] = f2bf(oacc[dt][r] * inv[r]);
    }
  }
}

// ---------------------------------------------------------------------------
// FFN gating in place on gu (N,8192) bf16 [gr|gi|ur|ui] -> hid cols [0,4096),
// vectorized bf16x8.
// ---------------------------------------------------------------------------
__global__ __launch_bounds__(256) void gate_kernel(unsigned short* __restrict__ gu) {
  int id = blockIdx.x * 256 + threadIdx.x;  // 0 .. kNT*2048/8 - 1
  int n = id >> 8, m8 = (id & 255) * 8;
  size_t row = (size_t)n * 8192;
  bf16x8 gr8 = *(const bf16x8*)&gu[row + m8];
  bf16x8 gi8 = *(const bf16x8*)&gu[row + 2048 + m8];
  bf16x8 ur8 = *(const bf16x8*)&gu[row + 4096 + m8];
  bf16x8 ui8 = *(const bf16x8*)&gu[row + 6144 + m8];
  unsigned short hr[8], hi[8];
#pragma unroll
  for (int e = 0; e < 8; e++) {
    float gr = bf2f((unsigned short)gr8[e]);
    float gi = bf2f((unsigned short)gi8[e]);
    float ur = bf2f((unsigned short)ur8[e]);
    float ui = bf2f((unsigned short)ui8[e]);
    float mag = sqrtf(gr * gr + gi * gi);
    float s = 1.f / (1.f + __expf(-mag));
    float gar = gr * s, gai = gi * s;
    hr[e] = f2bf(gar * ur - gai * ui);
    hi[e] = f2bf(gar * ui + gai * ur);
  }
  *(bf16x8*)&gu[row + m8] = *(const bf16x8*)hr;
  *(bf16x8*)&gu[row + 2048 + m8] = *(const bf16x8*)hi;
}

// ---------------------------------------------------------------------------
// Launcher
// ---------------------------------------------------------------------------
extern "C" void kernel_launch(void* const* d_in, const int* in_sizes, int n_in,
                              void* d_out, int out_size, void* d_ws, size_t ws_size,
                              hipStream_t stream) {
  const float* x_real = (const float*)d_in[0];
  const float* x_imag = (const float*)d_in[1];
  const float* ln1_gr = (const float*)d_in[2];
  const float* ln1_gi = (const float*)d_in[3];
  const float* ln1_br = (const float*)d_in[4];
  const float* ln1_bi = (const float*)d_in[5];
  const float* q_lm = (const float*)d_in[6];
  const float* q_ph = (const float*)d_in[7];
  const float* q_bm = (const float*)d_in[8];
  const float* q_bp = (const float*)d_in[9];
  const float* k_lm = (const float*)d_in[10];
  const float* k_ph = (const float*)d_in[11];
  const float* k_bm = (const float*)d_in[12];
  const float* k_bp = (const float*)d_in[13];
  const float* v_lm = (const float*)d_in[14];
  const float* v_ph = (const float*)d_in[15];
  const float* v_bm = (const float*)d_in[16];
  const float* v_bp = (const float*)d_in[17];
  const float* o_lm = (const float*)d_in[18];
  const float* o_ph = (const float*)d_in[19];
  const float* o_bm = (const float*)d_in[20];
  const float* o_bp = (const float*)d_in[21];
  const float* ln2_gr = (const float*)d_in[22];
  const float* ln2_gi = (const float*)d_in[23];
  const float* ln2_br = (const float*)d_in[24];
  const float* ln2_bi = (const float*)d_in[25];
  const float* gate_lm = (const float*)d_in[26];
  const float* gate_ph = (const float*)d_in[27];
  const float* up_lm = (const float*)d_in[28];
  const float* up_ph = (const float*)d_in[29];
  const float* down_lm = (const float*)d_in[30];
  const float* down_ph = (const float*)d_in[31];

  // ---- workspace layout (bytes), total 125,845,504 ----
  char* wsb = (char*)d_ws;
  unsigned short* Wqkv = (unsigned short*)(wsb + 0);           // 3072x1024 bf16
  unsigned short* Wo   = (unsigned short*)(wsb + 6291456);     // 1024x1024
  unsigned short* Wgu  = (unsigned short*)(wsb + 8388608);     // 8192x1024
  unsigned short* Wd   = (unsigned short*)(wsb + 25165824);    // 1024x4096
  float* qkvBias = (float*)(wsb + 33554432);                   // 3072 fp32
  float* oBias   = (float*)(wsb + 33566720);                   // 1024 fp32
  float* res     = (float*)(wsb + 33570816);                   // 4096x1024 fp32
  unsigned short* H = (unsigned short*)(wsb + 50348032);       // 4096x1024 bf16
  char* big = wsb + 58736640;                                  // 64 MiB region
  unsigned short* qkv     = (unsigned short*)big;              // 4096x3072 bf16
  unsigned short* attnout = (unsigned short*)(big + 25165824); // 4096x1024 bf16
  unsigned short* vtb     = (unsigned short*)(big + 33554432); // 4x8x128x1024 bf16
  unsigned short* gu      = (unsigned short*)big;              // 4096x8192 bf16 (aliases, later)

  float* outf = (float*)d_out;  // (2, 4096, 512)

  // 1) build weights + biases
  build_wcat_perm_kernel<<<1024, 256, 0, stream>>>(q_lm, q_ph, Wqkv, 0);
  build_wcat_perm_kernel<<<1024, 256, 0, stream>>>(k_lm, k_ph, Wqkv, 1);
  build_wcat_perm_kernel<<<1024, 256, 0, stream>>>(v_lm, v_ph, Wqkv, 2);
  build_wcat_kernel<<<kDD / 256, 256, 0, stream>>>(o_lm, o_ph, Wo, 512, 512, 9);
  build_wcat_kernel<<<kDH / 256, 256, 0, stream>>>(gate_lm, gate_ph, Wgu, 2048, 512, 9);
  build_wcat_kernel<<<kDH / 256, 256, 0, stream>>>(up_lm, up_ph, Wgu + (size_t)4096 * 1024, 2048, 512, 9);
  build_wcat_kernel<<<kDH / 256, 256, 0, stream>>>(down_lm, down_ph, Wd, 512, 2048, 11);
  build_bias_perm_kernel<<<2, 256, 0, stream>>>(q_bm, q_bp, qkvBias, 0);
  build_bias_perm_kernel<<<2, 256, 0, stream>>>(k_bm, k_bp, qkvBias, 1);
  build_bias_perm_kernel<<<2, 256, 0, stream>>>(v_bm, v_bp, qkvBias, 2);
  build_bias_kernel<<<2, 256, 0, stream>>>(o_bm, o_bp, oBias, 512);

  // 2) LN1: x -> H (bf16 cat)
  cln_kernel<<<kNT / 4, 256, 0, stream>>>(x_real, x_imag, 512, ln1_gr, ln1_gi, ln1_br, ln1_bi, H);

  // 3) QKV fused GEMM (head-permuted cols; V written transposed to vtb)
  {
    dim3 g(3072 / 128, kNT / 128);
    cgemm_mfma_kernel<<<g, 256, 0, stream>>>(H, 1024, Wqkv, 1024, qkvBias, 3,
                                             nullptr, nullptr, qkv, 3072, nullptr, vtb);
  }

  // 4) RoPE in place on q,k
  rope_kernel<<<(kNT * kH * 32) / 256, 256, 0, stream>>>(qkv);

  // 5) MFMA flash attention -> attnout
  attn_mfma_kernel<<<kB * kH * (kS / 64), 256, 0, stream>>>(qkv, vtb, attnout);

  // 6) O-proj + x residual -> res fp32
  {
    dim3 g(1024 / 128, kNT / 128);
    cgemm_mfma_kernel<<<g, 256, 0, stream>>>(attnout, 1024, Wo, 1024, oBias, 1,
                                             x_real, x_imag, nullptr, 0, res, nullptr);
  }

  // 7) LN2: res -> H
  cln_kernel<<<kNT / 4, 256, 0, stream>>>(res, res + 512, 1024, ln2_gr, ln2_gi, ln2_br, ln2_bi, H);

  // 8) gate+up fused GEMM -> gu
  {
    dim3 g(8192 / 128, kNT / 128);
    cgemm_mfma_kernel<<<g, 256, 0, stream>>>(H, 1024, Wgu, 1024, nullptr, 0,
                                             nullptr, nullptr, gu, 8192, nullptr, nullptr);
  }

  // 9) gating in place (vectorized)
  gate_kernel<<<(kNT * kHID / 8) / 256, 256, 0, stream>>>(gu);

  // 10) down GEMM + residual -> d_out fp32
  {
    dim3 g(1024 / 128, kNT / 128);
    cgemm_mfma_kernel<<<g, 256, 0, stream>>>(gu, 8192, Wd, 4096, nullptr, 2,
                                             res, nullptr, nullptr, 0, outf, nullptr);
  }
}

// Round 5
// 483.067 us; speedup vs baseline: 1.2322x; 1.2322x over previous
//
#include <hip/hip_runtime.h>
#include <math.h>

// Problem constants: B=4, S=1024, D=512, H=8, HD=64, HID=2048
#define kB 4
#define kS 1024
#define kD 512
#define kH 8
#define kHD 64
#define kHID 2048
#define kNT (kB * kS)          // 4096 tokens
#define kBSD (kNT * kD)        // 2,097,152

typedef __attribute__((ext_vector_type(8))) short bf16x8;
typedef __attribute__((ext_vector_type(4))) float f32x4;

#define AS1 __attribute__((address_space(1)))
#define AS3 __attribute__((address_space(3)))

__device__ __forceinline__ float bf2f(unsigned short u) {
  return __uint_as_float(((unsigned int)u) << 16);
}
__device__ __forceinline__ unsigned short f2bf(float f) {
  unsigned int u = __float_as_uint(f);
  u += 0x7fffu + ((u >> 16) & 1u);   // RNE
  return (unsigned short)(u >> 16);
}

// ---------------------------------------------------------------------------
// Fused weight build A: QKV (head-permuted) + O (standard cat).
// grid 4096 x 256. seg = gid>>18: 0=q,1=k,2=v (perm), 3=o (std).
// ---------------------------------------------------------------------------
__global__ __launch_bounds__(256) void build_wA_kernel(
    const float* __restrict__ qlm, const float* __restrict__ qph,
    const float* __restrict__ klm, const float* __restrict__ kph,
    const float* __restrict__ vlm, const float* __restrict__ vph,
    const float* __restrict__ olm, const float* __restrict__ oph,
    unsigned short* __restrict__ Wqkv, unsigned short* __restrict__ Wo) {
  int gid = blockIdx.x * 256 + threadIdx.x;
  int seg = gid >> 18;
  int id = gid & 262143;
  const float* lm = seg == 0 ? qlm : seg == 1 ? klm : seg == 2 ? vlm : olm;
  const float* ph = seg == 0 ? qph : seg == 1 ? kph : seg == 2 ? vph : oph;
  float mm = __expf(lm[id]);
  float s, c;
  __sincosf(ph[id], &s, &c);
  float wr = mm * c, wi = mm * s;
  int m = id >> 9, k = id & 511;
  if (seg < 3) {
    int h = m >> 6, d = m & 63;
    size_t rowR = (size_t)seg * 1024 + h * 128 + d;
    size_t rowI = rowR + 64;
    Wqkv[rowR * 1024 + k] = f2bf(wr);
    Wqkv[rowR * 1024 + 512 + k] = f2bf(-wi);
    Wqkv[rowI * 1024 + k] = f2bf(wi);
    Wqkv[rowI * 1024 + 512 + k] = f2bf(wr);
  } else {
    Wo[(size_t)m * 1024 + k] = f2bf(wr);
    Wo[(size_t)m * 1024 + 512 + k] = f2bf(-wi);
    Wo[(size_t)(512 + m) * 1024 + k] = f2bf(wi);
    Wo[(size_t)(512 + m) * 1024 + 512 + k] = f2bf(wr);
  }
}

// ---------------------------------------------------------------------------
// Fused weight build B: gate+up (rows interleaved as quadruples 4j..4j+3 =
// gate_r, gate_i, up_r, up_i) + down (K interleaved as pairs 2j,2j+1 = hr,hi).
// grid 12288 x 256. seg = gid>>20: 0=gate,1=up,2=down.
// ---------------------------------------------------------------------------
__global__ __launch_bounds__(256) void build_wB_kernel(
    const float* __restrict__ glm, const float* __restrict__ gph,
    const float* __restrict__ ulm, const float* __restrict__ uph,
    const float* __restrict__ dlm, const float* __restrict__ dph,
    unsigned short* __restrict__ Wgu, unsigned short* __restrict__ Wd) {
  int gid = blockIdx.x * 256 + threadIdx.x;
  int seg = gid >> 20;
  int id = gid & 1048575;
  const float* lm = seg == 0 ? glm : seg == 1 ? ulm : dlm;
  const float* ph = seg == 0 ? gph : seg == 1 ? uph : dph;
  float mm = __expf(lm[id]);
  float s, c;
  __sincosf(ph[id], &s, &c);
  float wr = mm * c, wi = mm * s;
  if (seg < 2) {
    int j = id >> 9, k = id & 511;
    size_t r0 = (size_t)(4 * j + 2 * seg);  // gate -> 4j,4j+1 ; up -> 4j+2,4j+3
    Wgu[r0 * 1024 + k] = f2bf(wr);
    Wgu[r0 * 1024 + 512 + k] = f2bf(-wi);
    Wgu[(r0 + 1) * 1024 + k] = f2bf(wi);
    Wgu[(r0 + 1) * 1024 + 512 + k] = f2bf(wr);
  } else {
    int m = id >> 11, j = id & 2047;
    Wd[(size_t)m * 4096 + 2 * j] = f2bf(wr);
    Wd[(size_t)m * 4096 + 2 * j + 1] = f2bf(-wi);
    Wd[(size_t)(512 + m) * 4096 + 2 * j] = f2bf(wi);
    Wd[(size_t)(512 + m) * 4096 + 2 * j + 1] = f2bf(wr);
  }
}

// ---------------------------------------------------------------------------
// Fused bias build: qkv (head-permuted) + o. grid 8 x 256.
// ---------------------------------------------------------------------------
__global__ __launch_bounds__(256) void build_bias_all_kernel(
    const float* __restrict__ qbm, const float* __restrict__ qbp,
    const float* __restrict__ kbm, const float* __restrict__ kbp,
    const float* __restrict__ vbm, const float* __restrict__ vbp,
    const float* __restrict__ obm, const float* __restrict__ obp,
    float* __restrict__ qkvBias, float* __restrict__ oBias) {
  int gid = blockIdx.x * 256 + threadIdx.x;
  int seg = gid >> 9, m = gid & 511;
  const float* bm = seg == 0 ? qbm : seg == 1 ? kbm : seg == 2 ? vbm : obm;
  const float* bp = seg == 0 ? qbp : seg == 1 ? kbp : seg == 2 ? vbp : obp;
  float s, c;
  __sincosf(bp[m], &s, &c);
  float br = bm[m] * c, bi = bm[m] * s;
  if (seg < 3) {
    int h = m >> 6, d = m & 63;
    qkvBias[seg * 1024 + h * 128 + d] = br;
    qkvBias[seg * 1024 + h * 128 + 64 + d] = bi;
  } else {
    oBias[m] = br;
    oBias[512 + m] = bi;
  }
}

// ---------------------------------------------------------------------------
// Complex LayerNorm: one WAVE per token, shfl butterflies, no barriers.
// fp32 in (row stride) -> bf16 (N,1024) [r|i]. grid = NT/4.
// ---------------------------------------------------------------------------
__global__ __launch_bounds__(256) void cln_kernel(
    const float* __restrict__ xr, const float* __restrict__ xi, int stride,
    const float* __restrict__ g_r, const float* __restrict__ g_i,
    const float* __restrict__ b_r, const float* __restrict__ b_i,
    unsigned short* __restrict__ out) {
  int w = threadIdx.x >> 6, lane = threadIdx.x & 63;
  int t = blockIdx.x * 4 + w;
  int d0 = lane * 8;
  const float* xrt = xr + (size_t)t * stride + d0;
  const float* xit = xi + (size_t)t * stride + d0;
  float4 a0 = *(const float4*)&xrt[0];
  float4 a1 = *(const float4*)&xrt[4];
  float4 c0 = *(const float4*)&xit[0];
  float4 c1 = *(const float4*)&xit[4];

  float s1 = a0.x + a0.y + a0.z + a0.w + a1.x + a1.y + a1.z + a1.w;
  float s2 = c0.x + c0.y + c0.z + c0.w + c1.x + c1.y + c1.z + c1.w;
#pragma unroll
  for (int off = 1; off < 64; off <<= 1) {
    s1 += __shfl_xor(s1, off);
    s2 += __shfl_xor(s2, off);
  }
  float mr = s1 * (1.f / kD), mi = s2 * (1.f / kD);

  float ar[8] = {a0.x, a0.y, a0.z, a0.w, a1.x, a1.y, a1.z, a1.w};
  float ai[8] = {c0.x, c0.y, c0.z, c0.w, c1.x, c1.y, c1.z, c1.w};
  float v = 0.f;
#pragma unroll
  for (int e = 0; e < 8; e++) {
    float cr = ar[e] - mr, ci = ai[e] - mi;
    v += cr * cr + ci * ci;
  }
#pragma unroll
  for (int off = 1; off < 64; off <<= 1) v += __shfl_xor(v, off);
  float inv = rsqrtf(v * (1.f / kD) + 1e-6f);

  float4 g0 = *(const float4*)&g_r[d0];
  float4 g1 = *(const float4*)&g_r[d0 + 4];
  float4 h0 = *(const float4*)&g_i[d0];
  float4 h1 = *(const float4*)&g_i[d0 + 4];
  float4 p0 = *(const float4*)&b_r[d0];
  float4 p1 = *(const float4*)&b_r[d0 + 4];
  float4 q0 = *(const float4*)&b_i[d0];
  float4 q1 = *(const float4*)&b_i[d0 + 4];
  float gr[8] = {g0.x, g0.y, g0.z, g0.w, g1.x, g1.y, g1.z, g1.w};
  float gi[8] = {h0.x, h0.y, h0.z, h0.w, h1.x, h1.y, h1.z, h1.w};
  float br[8] = {p0.x, p0.y, p0.z, p0.w, p1.x, p1.y, p1.z, p1.w};
  float bi[8] = {q0.x, q0.y, q0.z, q0.w, q1.x, q1.y, q1.z, q1.w};

  unsigned short pr[8], pi[8];
#pragma unroll
  for (int e = 0; e < 8; e++) {
    float nr = (ar[e] - mr) * inv;
    float ni = (ai[e] - mi) * inv;
    pr[e] = f2bf(nr * gr[e] - ni * gi[e] + br[e]);
    pi[e] = f2bf(nr * gi[e] + ni * gr[e] + bi[e]);
  }
  unsigned short* ot = out + (size_t)t * 1024 + d0;
  *(bf16x8*)&ot[0] = *(const bf16x8*)pr;
  *(bf16x8*)&ot[512] = *(const bf16x8*)pi;
}

// ---------------------------------------------------------------------------
// bf16 MFMA GEMM, 128x128 tile, BK=64, 4 waves, 16x16x32 MFMA.
// LDS rows are 128B (bank-degenerate) -> 8-granule XOR swizzle applied on the
// staging GLOBAL address; ds_read picks granule G^(row&7).
// Epilogue modes:
//   3: QKV: cols<2048 -> direct bf16 stores (ldo=3072); cols>=2048 -> V
//      transposed ushort4 stores to vt[b][h][dcat][s]
//   4: gateup: cols are (gr,gi,ur,ui) quadruples; gate via 3x shfl_xor,
//      write hid (N,4096) interleaved (hr,hi) pairs
// ---------------------------------------------------------------------------
__global__ __launch_bounds__(256) void cgemm_mfma_kernel(
    const unsigned short* __restrict__ X, int ldx,
    const unsigned short* __restrict__ Wt, int K,
    const float* __restrict__ bias, int mode,
    unsigned short* __restrict__ outb, int ldo,
    unsigned short* __restrict__ vtb) {
  __shared__ unsigned short Xs[128 * 64];
  __shared__ unsigned short Ws[128 * 64];

  const int tid = threadIdx.x;
  const int w = tid >> 6;
  const int lane = tid & 63;
  const int quad = lane >> 4;
  const int l15 = lane & 15;
  const int m0 = blockIdx.x * 128;
  const int n0 = blockIdx.y * 128;
  const int wm = (w & 1) * 64;
  const int wn = (w >> 1) * 64;

  // staging: chunk(16B) -> row=chunk>>3, gpos=chunk&7; global granule = gpos^(row&7)
  const int rsub = lane >> 3;                    // 0..7
  const int grow = w * 32 + rsub;                // + t*8 per inst
  const int gcol = ((lane & 7) ^ rsub) * 8;      // swizzled global granule
  const unsigned short* gx = X + (size_t)(n0 + grow) * ldx + gcol;
  const unsigned short* gw = Wt + (size_t)(m0 + grow) * K + gcol;

  const int rg = (l15 & 7);                      // read-side swizzle key

  f32x4 acc[4][4];
#pragma unroll
  for (int i = 0; i < 4; i++)
#pragma unroll
    for (int j = 0; j < 4; j++) acc[i][j] = (f32x4){0.f, 0.f, 0.f, 0.f};

  for (int k0 = 0; k0 < K; k0 += 64) {
    __syncthreads();
#pragma unroll
    for (int t = 0; t < 4; t++) {
      __builtin_amdgcn_global_load_lds((const AS1 void*)(gx + (size_t)t * 8 * ldx + k0),
                                       (AS3 void*)&Xs[w * 2048 + t * 512], 16, 0, 0);
      __builtin_amdgcn_global_load_lds((const AS1 void*)(gw + (size_t)t * 8 * K + k0),
                                       (AS3 void*)&Ws[w * 2048 + t * 512], 16, 0, 0);
    }
    __syncthreads();

#pragma unroll
    for (int ks = 0; ks < 2; ks++) {
      const int gsel = ((ks * 4 + quad) ^ rg) * 8;
      bf16x8 af[4], bf[4];
#pragma unroll
      for (int t = 0; t < 4; t++) {
        af[t] = *(const bf16x8*)&Xs[(wn + t * 16 + l15) * 64 + gsel];
        bf[t] = *(const bf16x8*)&Ws[(wm + t * 16 + l15) * 64 + gsel];
      }
#pragma unroll
      for (int i = 0; i < 4; i++)
#pragma unroll
        for (int j = 0; j < 4; j++)
          acc[i][j] = __builtin_amdgcn_mfma_f32_16x16x32_bf16(af[i], bf[j], acc[i][j], 0, 0, 0);
    }
  }

  // epilogue: D mapping col=lane&15 (feature), row=(lane>>4)*4+reg (token)
  if (mode == 4) {
    // gating: quadruple T=col>>2, role=col&3 (= l15&3); partners via shfl
#pragma unroll
    for (int j = 0; j < 4; ++j) {
      int col = m0 + wm + j * 16 + l15;
      int role = col & 3;
      int T2 = (col >> 2) * 2 + role;  // output col for roles 0/1
#pragma unroll
      for (int i = 0; i < 4; ++i) {
        int row0 = n0 + wn + i * 16 + quad * 4;
#pragma unroll
        for (int r = 0; r < 4; ++r) {
          float v = acc[i][j][r];
          float b = __shfl_xor(v, 1);
          float c = __shfl_xor(v, 2);
          float d = __shfl_xor(c, 1);
          float s = 1.f / (1.f + __expf(-sqrtf(v * v + b * b)));
          float hv = (role == 0) ? (v * c - b * d) * s : (b * c + v * d) * s;
          if (role < 2)
            outb[(size_t)(row0 + r) * ldo + T2] = f2bf(hv);
        }
      }
    }
  } else {
#pragma unroll
    for (int j = 0; j < 4; ++j) {
      int col = m0 + wm + j * 16 + l15;
      float bv = bias ? bias[col] : 0.f;
      if (col >= 2048) {
        // V: transposed stores vt[b][h][dcat][s]
        int hh = (col - 2048) >> 7, dcat = (col - 2048) & 127;
#pragma unroll
        for (int i = 0; i < 4; ++i) {
          int row0 = n0 + wn + i * 16 + quad * 4;
          int bb = row0 >> 10, s0 = row0 & 1023;
          ushort4 pk;
          pk.x = f2bf(acc[i][j][0] + bv);
          pk.y = f2bf(acc[i][j][1] + bv);
          pk.z = f2bf(acc[i][j][2] + bv);
          pk.w = f2bf(acc[i][j][3] + bv);
          *(ushort4*)&vtb[(size_t)((bb * 8 + hh) * 128 + dcat) * 1024 + s0] = pk;
        }
      } else {
#pragma unroll
        for (int i = 0; i < 4; ++i) {
          int row0 = n0 + wn + i * 16 + quad * 4;
#pragma unroll
          for (int r = 0; r < 4; ++r)
            outb[(size_t)(row0 + r) * ldo + col] = f2bf(acc[i][j][r] + bv);
        }
      }
    }
  }
}

// ---------------------------------------------------------------------------
// bf16 MFMA GEMM, 64x128 tile (N=64), BK=64, 4 waves (2n x 2m of 32x64).
// fp32 epilogues only:
//   1: O-proj: outf (N,1024) = acc + bias + x residual (resr/resi stride 512)
//   2: down:   d_out split halves = acc + resr[row*1024+col]
// Used for the 256-block GEMMs to get 512 blocks (2/CU).
// ---------------------------------------------------------------------------
__global__ __launch_bounds__(256) void cgemm_mfma_n64_kernel(
    const unsigned short* __restrict__ X, int ldx,
    const unsigned short* __restrict__ Wt, int K,
    const float* __restrict__ bias, int mode,
    const float* __restrict__ resr, const float* __restrict__ resi,
    float* __restrict__ outf) {
  __shared__ unsigned short Xs[64 * 64];
  __shared__ unsigned short Ws[128 * 64];

  const int tid = threadIdx.x;
  const int w = tid >> 6;
  const int lane = tid & 63;
  const int quad = lane >> 4;
  const int l15 = lane & 15;
  const int m0 = blockIdx.x * 128;
  const int n0 = blockIdx.y * 64;
  const int wm = (w & 1) * 64;
  const int wn = (w >> 1) * 32;

  const int rsub = lane >> 3;
  const int gcol = ((lane & 7) ^ rsub) * 8;
  const unsigned short* gx = X + (size_t)(n0 + w * 16 + rsub) * ldx + gcol;   // 2 insts
  const unsigned short* gw = Wt + (size_t)(m0 + w * 32 + rsub) * K + gcol;    // 4 insts
  const int rg = (l15 & 7);

  f32x4 acc[2][4];
#pragma unroll
  for (int i = 0; i < 2; i++)
#pragma unroll
    for (int j = 0; j < 4; j++) acc[i][j] = (f32x4){0.f, 0.f, 0.f, 0.f};

  for (int k0 = 0; k0 < K; k0 += 64) {
    __syncthreads();
#pragma unroll
    for (int t = 0; t < 2; t++)
      __builtin_amdgcn_global_load_lds((const AS1 void*)(gx + (size_t)t * 8 * ldx + k0),
                                       (AS3 void*)&Xs[w * 1024 + t * 512], 16, 0, 0);
#pragma unroll
    for (int t = 0; t < 4; t++)
      __builtin_amdgcn_global_load_lds((const AS1 void*)(gw + (size_t)t * 8 * K + k0),
                                       (AS3 void*)&Ws[w * 2048 + t * 512], 16, 0, 0);
    __syncthreads();

#pragma unroll
    for (int ks = 0; ks < 2; ks++) {
      const int gsel = ((ks * 4 + quad) ^ rg) * 8;
      bf16x8 af[2], bf[4];
#pragma unroll
      for (int t = 0; t < 2; t++)
        af[t] = *(const bf16x8*)&Xs[(wn + t * 16 + l15) * 64 + gsel];
#pragma unroll
      for (int t = 0; t < 4; t++)
        bf[t] = *(const bf16x8*)&Ws[(wm + t * 16 + l15) * 64 + gsel];
#pragma unroll
      for (int i = 0; i < 2; i++)
#pragma unroll
        for (int j = 0; j < 4; j++)
          acc[i][j] = __builtin_amdgcn_mfma_f32_16x16x32_bf16(af[i], bf[j], acc[i][j], 0, 0, 0);
    }
  }

#pragma unroll
  for (int j = 0; j < 4; ++j) {
    int col = m0 + wm + j * 16 + l15;
    float bv = bias ? bias[col] : 0.f;
#pragma unroll
    for (int i = 0; i < 2; ++i) {
      int row0 = n0 + wn + i * 16 + quad * 4;
#pragma unroll
      for (int r = 0; r < 4; ++r) {
        int row = row0 + r;
        float val = acc[i][j][r] + bv;
        if (mode == 1) {
          float xres = (col < 512) ? resr[(size_t)row * 512 + col]
                                   : resi[(size_t)row * 512 + col - 512];
          outf[(size_t)row * 1024 + col] = val + xres;
        } else {
          float rv = resr[(size_t)row * 1024 + col] + val;
          size_t dd = (col < 512) ? ((size_t)row * 512 + col)
                                  : ((size_t)kBSD + (size_t)row * 512 + (col - 512));
          outf[dd] = rv;
        }
      }
    }
  }
}

// ---------------------------------------------------------------------------
// RoPE in place on qkv (N,3072), head-permuted layout.
// ---------------------------------------------------------------------------
__global__ __launch_bounds__(256) void rope_kernel(unsigned short* __restrict__ qkv) {
  int idx = blockIdx.x * 256 + threadIdx.x;
  int i = idx & 31;
  int h = (idx >> 5) & 7;
  int tok = idx >> 8;
  int s = tok & (kS - 1);
  float inv = __expf(-(float)i * (9.210340371976184f / 32.0f));
  float f = (float)s * inv;
  float sn, cs;
  __sincosf(f, &sn, &cs);
  size_t base0 = (size_t)tok * 3072 + h * 128 + i;
  const int offs[4] = {0, 64, 1024, 1088};  // qr, qi, kr, ki
#pragma unroll
  for (int comp = 0; comp < 4; comp++) {
    size_t base = base0 + offs[comp];
    float x0 = bf2f(qkv[base]), x1 = bf2f(qkv[base + 32]);
    qkv[base] = f2bf(x0 * cs - x1 * sn);
    qkv[base + 32] = f2bf(x1 * cs + x0 * sn);
  }
}

// ---------------------------------------------------------------------------
// MFMA flash attention (causal, Hermitian). Unchanged from R3 (works).
// ---------------------------------------------------------------------------
__global__ __launch_bounds__(256) void attn_mfma_kernel(
    const unsigned short* __restrict__ qkv,   // (4096, 3072)
    const unsigned short* __restrict__ vt,    // (4,8,128,1024)
    unsigned short* __restrict__ out) {       // (4096, 1024) [ar|ai]
  __shared__ unsigned short Ks[32 * 136];
  __shared__ unsigned short Vs[128 * 40];
  __shared__ unsigned short Ps[4 * 16 * 40];

  const int tid = threadIdx.x;
  const int w = tid >> 6;
  const int lane = tid & 63;
  const int quad = lane >> 4;
  const int l15 = lane & 15;

  int bid = blockIdx.x;
  int qt = bid & 15;
  if ((bid >> 4) & 1) qt = 15 - qt;
  const int h = (bid >> 4) & 7;
  const int b = bid >> 7;
  const int q0 = qt * 64;
  const int wrow0 = q0 + w * 16;

  bf16x8 qa[4];
  {
    size_t base = (size_t)(b * kS + wrow0 + l15) * 3072 + h * 128;
#pragma unroll
    for (int ks = 0; ks < 4; ks++)
      qa[ks] = *(const bf16x8*)&qkv[base + ks * 32 + quad * 8];
  }

  f32x4 oacc[8];
#pragma unroll
  for (int dt = 0; dt < 8; dt++) oacc[dt] = (f32x4){0.f, 0.f, 0.f, 0.f};
  float m_r[4] = {-1e30f, -1e30f, -1e30f, -1e30f};
  float l_r[4] = {0.f, 0.f, 0.f, 0.f};

  const int ktmax_blk = (q0 + 63) >> 5;
  const int ktmax_wav = (wrow0 + 15) >> 5;
  const float cexp = 0.1803368801f;  // (1/sqrt(64)) * log2(e)

  const unsigned short* gkbase = qkv + 1024 + h * 128;
  const unsigned short* gvbase = vt + (size_t)((b * 8 + h) * 128) * 1024;

  for (int kt = 0; kt <= ktmax_blk; ++kt) {
    const int k0 = kt * 32;
    __syncthreads();
    {
      int ch = tid * 2;
      int r = ch >> 4, cc = (ch & 15) * 8;
      const unsigned short* gk = gkbase + (size_t)(b * kS + k0) * 3072;
      *(bf16x8*)&Ks[r * 136 + cc] = *(const bf16x8*)&gk[(size_t)r * 3072 + cc];
      int r2 = (ch + 1) >> 4, cc2 = ((ch + 1) & 15) * 8;
      *(bf16x8*)&Ks[r2 * 136 + cc2] = *(const bf16x8*)&gk[(size_t)r2 * 3072 + cc2];
      int vr = ch >> 2, vc = (ch & 3) * 8;
      *(bf16x8*)&Vs[vr * 40 + vc] = *(const bf16x8*)&gvbase[(size_t)vr * 1024 + k0 + vc];
      int vr2 = (ch + 1) >> 2, vc2 = ((ch + 1) & 3) * 8;
      *(bf16x8*)&Vs[vr2 * 40 + vc2] = *(const bf16x8*)&gvbase[(size_t)vr2 * 1024 + k0 + vc2];
    }
    __syncthreads();

    if (kt <= ktmax_wav) {
      f32x4 s[2];
      s[0] = (f32x4){0.f, 0.f, 0.f, 0.f};
      s[1] = (f32x4){0.f, 0.f, 0.f, 0.f};
#pragma unroll
      for (int ns = 0; ns < 2; ns++)
#pragma unroll
        for (int ks = 0; ks < 4; ks++) {
          bf16x8 kb = *(const bf16x8*)&Ks[(ns * 16 + l15) * 136 + ks * 32 + quad * 8];
          s[ns] = __builtin_amdgcn_mfma_f32_16x16x32_bf16(qa[ks], kb, s[ns], 0, 0, 0);
        }

      if (k0 + 31 > wrow0) {
#pragma unroll
        for (int r = 0; r < 4; r++) {
          int qrow = wrow0 + quad * 4 + r;
          if (k0 + l15 > qrow) s[0][r] = -1e30f;
          if (k0 + 16 + l15 > qrow) s[1][r] = -1e30f;
        }
      }

      float alpha[4];
#pragma unroll
      for (int r = 0; r < 4; r++) {
        float mx = fmaxf(s[0][r], s[1][r]);
        mx = fmaxf(mx, __shfl_xor(mx, 1));
        mx = fmaxf(mx, __shfl_xor(mx, 2));
        mx = fmaxf(mx, __shfl_xor(mx, 4));
        mx = fmaxf(mx, __shfl_xor(mx, 8));
        float mn = fmaxf(m_r[r], mx);
        float al = exp2f((m_r[r] - mn) * cexp);
        m_r[r] = mn;
        float p0 = exp2f((s[0][r] - mn) * cexp);
        float p1 = exp2f((s[1][r] - mn) * cexp);
        s[0][r] = p0;
        s[1][r] = p1;
        float rs = p0 + p1;
        rs += __shfl_xor(rs, 1);
        rs += __shfl_xor(rs, 2);
        rs += __shfl_xor(rs, 4);
        rs += __shfl_xor(rs, 8);
        l_r[r] = l_r[r] * al + rs;
        alpha[r] = al;
      }

#pragma unroll
      for (int dt = 0; dt < 8; dt++)
#pragma unroll
        for (int r = 0; r < 4; r++) oacc[dt][r] *= alpha[r];

      unsigned short* pw = &Ps[w * 640];
#pragma unroll
      for (int r = 0; r < 4; r++) {
        int q = quad * 4 + r;
        pw[q * 40 + l15] = f2bf(s[0][r]);
        pw[q * 40 + 16 + l15] = f2bf(s[1][r]);
      }
      bf16x8 pa = *(const bf16x8*)&pw[l15 * 40 + quad * 8];

#pragma unroll
      for (int dt = 0; dt < 8; dt++) {
        bf16x8 vb = *(const bf16x8*)&Vs[(dt * 16 + l15) * 40 + quad * 8];
        oacc[dt] = __builtin_amdgcn_mfma_f32_16x16x32_bf16(pa, vb, oacc[dt], 0, 0, 0);
      }
    }
  }

  float inv[4];
#pragma unroll
  for (int r = 0; r < 4; r++) inv[r] = 1.f / l_r[r];
#pragma unroll
  for (int dt = 0; dt < 8; dt++) {
    int dcat = dt * 16 + l15;
    int col = (dcat < 64) ? (h * 64 + dcat) : (512 + h * 64 + dcat - 64);
#pragma unroll
    for (int r = 0; r < 4; r++) {
      int tok = b * kS + wrow0 + quad * 4 + r;
      out[(size_t)tok * 1024 + col] = f2bf(oacc[dt][r] * inv[r]);
    }
  }
}

// ---------------------------------------------------------------------------
// Launcher
// ---------------------------------------------------------------------------
extern "C" void kernel_launch(void* const* d_in, const int* in_sizes, int n_in,
                              void* d_out, int out_size, void* d_ws, size_t ws_size,
                              hipStream_t stream) {
  const float* x_real = (const float*)d_in[0];
  const float* x_imag = (const float*)d_in[1];
  const float* ln1_gr = (const float*)d_in[2];
  const float* ln1_gi = (const float*)d_in[3];
  const float* ln1_br = (const float*)d_in[4];
  const float* ln1_bi = (const float*)d_in[5];
  const float* q_lm = (const float*)d_in[6];
  const float* q_ph = (const float*)d_in[7];
  const float* q_bm = (const float*)d_in[8];
  const float* q_bp = (const float*)d_in[9];
  const float* k_lm = (const float*)d_in[10];
  const float* k_ph = (const float*)d_in[11];
  const float* k_bm = (const float*)d_in[12];
  const float* k_bp = (const float*)d_in[13];
  const float* v_lm = (const float*)d_in[14];
  const float* v_ph = (const float*)d_in[15];
  const float* v_bm = (const float*)d_in[16];
  const float* v_bp = (const float*)d_in[17];
  const float* o_lm = (const float*)d_in[18];
  const float* o_ph = (const float*)d_in[19];
  const float* o_bm = (const float*)d_in[20];
  const float* o_bp = (const float*)d_in[21];
  const float* ln2_gr = (const float*)d_in[22];
  const float* ln2_gi = (const float*)d_in[23];
  const float* ln2_br = (const float*)d_in[24];
  const float* ln2_bi = (const float*)d_in[25];
  const float* gate_lm = (const float*)d_in[26];
  const float* gate_ph = (const float*)d_in[27];
  const float* up_lm = (const float*)d_in[28];
  const float* up_ph = (const float*)d_in[29];
  const float* down_lm = (const float*)d_in[30];
  const float* down_ph = (const float*)d_in[31];

  // ---- workspace layout (bytes) ----
  char* wsb = (char*)d_ws;
  unsigned short* Wqkv = (unsigned short*)(wsb + 0);           // 3072x1024 bf16
  unsigned short* Wo   = (unsigned short*)(wsb + 6291456);     // 1024x1024
  unsigned short* Wgu  = (unsigned short*)(wsb + 8388608);     // 8192x1024 (interleaved rows)
  unsigned short* Wd   = (unsigned short*)(wsb + 25165824);    // 1024x4096 (interleaved K)
  float* qkvBias = (float*)(wsb + 33554432);                   // 3072 fp32
  float* oBias   = (float*)(wsb + 33566720);                   // 1024 fp32
  float* res     = (float*)(wsb + 33570816);                   // 4096x1024 fp32
  unsigned short* H = (unsigned short*)(wsb + 50348032);       // 4096x1024 bf16
  char* big = wsb + 58736640;                                  // ~67 MiB region
  unsigned short* qkv     = (unsigned short*)big;              // 4096x3072 bf16
  unsigned short* attnout = (unsigned short*)(big + 25165824); // 4096x1024 bf16
  unsigned short* vtb     = (unsigned short*)(big + 33554432); // 4x8x128x1024 bf16
  unsigned short* hid     = (unsigned short*)big;              // 4096x4096 bf16 (aliases qkv+attnout, dead then)

  float* outf = (float*)d_out;  // (2, 4096, 512)

  // 1) fused builds
  build_wA_kernel<<<4096, 256, 0, stream>>>(q_lm, q_ph, k_lm, k_ph, v_lm, v_ph,
                                            o_lm, o_ph, Wqkv, Wo);
  build_wB_kernel<<<12288, 256, 0, stream>>>(gate_lm, gate_ph, up_lm, up_ph,
                                             down_lm, down_ph, Wgu, Wd);
  build_bias_all_kernel<<<8, 256, 0, stream>>>(q_bm, q_bp, k_bm, k_bp, v_bm, v_bp,
                                               o_bm, o_bp, qkvBias, oBias);

  // 2) LN1: x -> H
  cln_kernel<<<kNT / 4, 256, 0, stream>>>(x_real, x_imag, 512, ln1_gr, ln1_gi, ln1_br, ln1_bi, H);

  // 3) QKV fused GEMM (mode 3)
  {
    dim3 g(3072 / 128, kNT / 128);
    cgemm_mfma_kernel<<<g, 256, 0, stream>>>(H, 1024, Wqkv, 1024, qkvBias, 3, qkv, 3072, vtb);
  }

  // 4) RoPE
  rope_kernel<<<(kNT * kH * 32) / 256, 256, 0, stream>>>(qkv);

  // 5) attention -> attnout
  attn_mfma_kernel<<<kB * kH * (kS / 64), 256, 0, stream>>>(qkv, vtb, attnout);

  // 6) O-proj + x residual -> res fp32 (n64 variant, 512 blocks)
  {
    dim3 g(1024 / 128, kNT / 64);
    cgemm_mfma_n64_kernel<<<g, 256, 0, stream>>>(attnout, 1024, Wo, 1024, oBias, 1,
                                                 x_real, x_imag, res);
  }

  // 7) LN2: res -> H
  cln_kernel<<<kNT / 4, 256, 0, stream>>>(res, res + 512, 1024, ln2_gr, ln2_gi, ln2_br, ln2_bi, H);

  // 8) gate+up GEMM with fused gating (mode 4) -> hid (N,4096 interleaved)
  {
    dim3 g(8192 / 128, kNT / 128);
    cgemm_mfma_kernel<<<g, 256, 0, stream>>>(H, 1024, Wgu, 1024, nullptr, 4, hid, 4096, nullptr);
  }

  // 9) down GEMM + residual -> d_out (n64 variant, 512 blocks)
  {
    dim3 g(1024 / 128, kNT / 64);
    cgemm_mfma_n64_kernel<<<g, 256, 0, stream>>>(hid, 4096, Wd, 4096, nullptr, 2,
                                                 res, nullptr, outf);
  }
}

// Round 6
// 461.200 us; speedup vs baseline: 1.2907x; 1.0474x over previous
//
#include <hip/hip_runtime.h>
#include <math.h>

// Problem constants: B=4, S=1024, D=512, H=8, HD=64, HID=2048
#define kB 4
#define kS 1024
#define kD 512
#define kH 8
#define kHD 64
#define kHID 2048
#define kNT (kB * kS)          // 4096 tokens
#define kBSD (kNT * kD)        // 2,097,152

typedef __attribute__((ext_vector_type(8))) short bf16x8;
typedef __attribute__((ext_vector_type(4))) float f32x4;

#define AS1 __attribute__((address_space(1)))
#define AS3 __attribute__((address_space(3)))

__device__ __forceinline__ float bf2f(unsigned short u) {
  return __uint_as_float(((unsigned int)u) << 16);
}
__device__ __forceinline__ unsigned short f2bf(float f) {
  unsigned int u = __float_as_uint(f);
  u += 0x7fffu + ((u >> 16) & 1u);   // RNE
  return (unsigned short)(u >> 16);
}

// ---------------------------------------------------------------------------
// Fused weight build A: QKV (head-permuted) + O (standard cat).
// grid 4096 x 256. seg = gid>>18: 0=q,1=k,2=v (perm), 3=o (std).
// ---------------------------------------------------------------------------
__global__ __launch_bounds__(256) void build_wA_kernel(
    const float* __restrict__ qlm, const float* __restrict__ qph,
    const float* __restrict__ klm, const float* __restrict__ kph,
    const float* __restrict__ vlm, const float* __restrict__ vph,
    const float* __restrict__ olm, const float* __restrict__ oph,
    unsigned short* __restrict__ Wqkv, unsigned short* __restrict__ Wo) {
  int gid = blockIdx.x * 256 + threadIdx.x;
  int seg = gid >> 18;
  int id = gid & 262143;
  const float* lm = seg == 0 ? qlm : seg == 1 ? klm : seg == 2 ? vlm : olm;
  const float* ph = seg == 0 ? qph : seg == 1 ? kph : seg == 2 ? vph : oph;
  float mm = __expf(lm[id]);
  float s, c;
  __sincosf(ph[id], &s, &c);
  float wr = mm * c, wi = mm * s;
  int m = id >> 9, k = id & 511;
  if (seg < 3) {
    int h = m >> 6, d = m & 63;
    size_t rowR = (size_t)seg * 1024 + h * 128 + d;
    size_t rowI = rowR + 64;
    Wqkv[rowR * 1024 + k] = f2bf(wr);
    Wqkv[rowR * 1024 + 512 + k] = f2bf(-wi);
    Wqkv[rowI * 1024 + k] = f2bf(wi);
    Wqkv[rowI * 1024 + 512 + k] = f2bf(wr);
  } else {
    Wo[(size_t)m * 1024 + k] = f2bf(wr);
    Wo[(size_t)m * 1024 + 512 + k] = f2bf(-wi);
    Wo[(size_t)(512 + m) * 1024 + k] = f2bf(wi);
    Wo[(size_t)(512 + m) * 1024 + 512 + k] = f2bf(wr);
  }
}

// ---------------------------------------------------------------------------
// Fused weight build B.
// Wgu role-in-j layout: feature T (0..2047) lives in 64-row group g=T>>4 at
// row = g*64 + role*16 + (T&15), roles: 0=gate_r,1=gate_i,2=up_r,3=up_i.
// Wd: K interleaved as pairs 2j,2j+1 = (hr,hi).
// grid 12288 x 256. seg = gid>>20: 0=gate,1=up,2=down.
// ---------------------------------------------------------------------------
__global__ __launch_bounds__(256) void build_wB_kernel(
    const float* __restrict__ glm, const float* __restrict__ gph,
    const float* __restrict__ ulm, const float* __restrict__ uph,
    const float* __restrict__ dlm, const float* __restrict__ dph,
    unsigned short* __restrict__ Wgu, unsigned short* __restrict__ Wd) {
  int gid = blockIdx.x * 256 + threadIdx.x;
  int seg = gid >> 20;
  int id = gid & 1048575;
  const float* lm = seg == 0 ? glm : seg == 1 ? ulm : dlm;
  const float* ph = seg == 0 ? gph : seg == 1 ? uph : dph;
  float mm = __expf(lm[id]);
  float s, c;
  __sincosf(ph[id], &s, &c);
  float wr = mm * c, wi = mm * s;
  if (seg < 2) {
    int T = id >> 9, k = id & 511;
    size_t base = (size_t)(T >> 4) * 64 + (T & 15);
    size_t rR = base + (seg * 2 + 0) * 16;   // gate->role0, up->role2
    size_t rI = base + (seg * 2 + 1) * 16;   // gate->role1, up->role3
    Wgu[rR * 1024 + k] = f2bf(wr);
    Wgu[rR * 1024 + 512 + k] = f2bf(-wi);
    Wgu[rI * 1024 + k] = f2bf(wi);
    Wgu[rI * 1024 + 512 + k] = f2bf(wr);
  } else {
    int m = id >> 11, j = id & 2047;
    Wd[(size_t)m * 4096 + 2 * j] = f2bf(wr);
    Wd[(size_t)m * 4096 + 2 * j + 1] = f2bf(-wi);
    Wd[(size_t)(512 + m) * 4096 + 2 * j] = f2bf(wi);
    Wd[(size_t)(512 + m) * 4096 + 2 * j + 1] = f2bf(wr);
  }
}

// ---------------------------------------------------------------------------
// Fused bias build: qkv (head-permuted) + o. grid 8 x 256.
// ---------------------------------------------------------------------------
__global__ __launch_bounds__(256) void build_bias_all_kernel(
    const float* __restrict__ qbm, const float* __restrict__ qbp,
    const float* __restrict__ kbm, const float* __restrict__ kbp,
    const float* __restrict__ vbm, const float* __restrict__ vbp,
    const float* __restrict__ obm, const float* __restrict__ obp,
    float* __restrict__ qkvBias, float* __restrict__ oBias) {
  int gid = blockIdx.x * 256 + threadIdx.x;
  int seg = gid >> 9, m = gid & 511;
  const float* bm = seg == 0 ? qbm : seg == 1 ? kbm : seg == 2 ? vbm : obm;
  const float* bp = seg == 0 ? qbp : seg == 1 ? kbp : seg == 2 ? vbp : obp;
  float s, c;
  __sincosf(bp[m], &s, &c);
  float br = bm[m] * c, bi = bm[m] * s;
  if (seg < 3) {
    int h = m >> 6, d = m & 63;
    qkvBias[seg * 1024 + h * 128 + d] = br;
    qkvBias[seg * 1024 + h * 128 + 64 + d] = bi;
  } else {
    oBias[m] = br;
    oBias[512 + m] = bi;
  }
}

// ---------------------------------------------------------------------------
// Complex LayerNorm: one WAVE per token, shfl butterflies, no barriers.
// fp32 in (row stride) -> bf16 (N,1024) [r|i]. grid = NT/4.
// ---------------------------------------------------------------------------
__global__ __launch_bounds__(256) void cln_kernel(
    const float* __restrict__ xr, const float* __restrict__ xi, int stride,
    const float* __restrict__ g_r, const float* __restrict__ g_i,
    const float* __restrict__ b_r, const float* __restrict__ b_i,
    unsigned short* __restrict__ out) {
  int w = threadIdx.x >> 6, lane = threadIdx.x & 63;
  int t = blockIdx.x * 4 + w;
  int d0 = lane * 8;
  const float* xrt = xr + (size_t)t * stride + d0;
  const float* xit = xi + (size_t)t * stride + d0;
  float4 a0 = *(const float4*)&xrt[0];
  float4 a1 = *(const float4*)&xrt[4];
  float4 c0 = *(const float4*)&xit[0];
  float4 c1 = *(const float4*)&xit[4];

  float s1 = a0.x + a0.y + a0.z + a0.w + a1.x + a1.y + a1.z + a1.w;
  float s2 = c0.x + c0.y + c0.z + c0.w + c1.x + c1.y + c1.z + c1.w;
#pragma unroll
  for (int off = 1; off < 64; off <<= 1) {
    s1 += __shfl_xor(s1, off);
    s2 += __shfl_xor(s2, off);
  }
  float mr = s1 * (1.f / kD), mi = s2 * (1.f / kD);

  float ar[8] = {a0.x, a0.y, a0.z, a0.w, a1.x, a1.y, a1.z, a1.w};
  float ai[8] = {c0.x, c0.y, c0.z, c0.w, c1.x, c1.y, c1.z, c1.w};
  float v = 0.f;
#pragma unroll
  for (int e = 0; e < 8; e++) {
    float cr = ar[e] - mr, ci = ai[e] - mi;
    v += cr * cr + ci * ci;
  }
#pragma unroll
  for (int off = 1; off < 64; off <<= 1) v += __shfl_xor(v, off);
  float inv = rsqrtf(v * (1.f / kD) + 1e-6f);

  float4 g0 = *(const float4*)&g_r[d0];
  float4 g1 = *(const float4*)&g_r[d0 + 4];
  float4 h0 = *(const float4*)&g_i[d0];
  float4 h1 = *(const float4*)&g_i[d0 + 4];
  float4 p0 = *(const float4*)&b_r[d0];
  float4 p1 = *(const float4*)&b_r[d0 + 4];
  float4 q0 = *(const float4*)&b_i[d0];
  float4 q1 = *(const float4*)&b_i[d0 + 4];
  float gr[8] = {g0.x, g0.y, g0.z, g0.w, g1.x, g1.y, g1.z, g1.w};
  float gi[8] = {h0.x, h0.y, h0.z, h0.w, h1.x, h1.y, h1.z, h1.w};
  float br[8] = {p0.x, p0.y, p0.z, p0.w, p1.x, p1.y, p1.z, p1.w};
  float bi[8] = {q0.x, q0.y, q0.z, q0.w, q1.x, q1.y, q1.z, q1.w};

  unsigned short pr[8], pi[8];
#pragma unroll
  for (int e = 0; e < 8; e++) {
    float nr = (ar[e] - mr) * inv;
    float ni = (ai[e] - mi) * inv;
    pr[e] = f2bf(nr * gr[e] - ni * gi[e] + br[e]);
    pi[e] = f2bf(nr * gi[e] + ni * gr[e] + bi[e]);
  }
  unsigned short* ot = out + (size_t)t * 1024 + d0;
  *(bf16x8*)&ot[0] = *(const bf16x8*)pr;
  *(bf16x8*)&ot[512] = *(const bf16x8*)pi;
}

// ---------------------------------------------------------------------------
// bf16 MFMA GEMM, 128x128 tile, BK=64, 4 waves, 16x16x32 MFMA.
// XOR-swizzled staging (R5 structure, 0 bank conflicts).
// Epilogue modes:
//   3: QKV: q/k blocks (m0<2048) -> bias + FUSED ROPE + direct bf16 stores
//      (ldo=3072); V blocks -> bias + LDS-staged transpose to vt[b][h][dcat][s]
//   4: gateup: roles along j (0=gr,1=gi,2=ur,3=ui); per-lane gating, packed
//      (hr,hi) 4B store to hid (N,4096)
// ---------------------------------------------------------------------------
__global__ __launch_bounds__(256) void cgemm_mfma_kernel(
    const unsigned short* __restrict__ X, int ldx,
    const unsigned short* __restrict__ Wt, int K,
    const float* __restrict__ bias, int mode,
    unsigned short* __restrict__ outb, int ldo,
    unsigned short* __restrict__ vtb) {
  __shared__ unsigned short Sh[128 * 64 * 2];   // Xs | Ws, 32 KB
  unsigned short* Xs = Sh;
  unsigned short* Ws = Sh + 8192;

  const int tid = threadIdx.x;
  const int w = tid >> 6;
  const int lane = tid & 63;
  const int quad = lane >> 4;
  const int l15 = lane & 15;
  const int m0 = blockIdx.x * 128;
  const int n0 = blockIdx.y * 128;
  const int wm = (w & 1) * 64;
  const int wn = (w >> 1) * 64;

  const int rsub = lane >> 3;                    // 0..7
  const int grow = w * 32 + rsub;                // + t*8 per inst
  const int gcol = ((lane & 7) ^ rsub) * 8;      // swizzled global granule
  const unsigned short* gx = X + (size_t)(n0 + grow) * ldx + gcol;
  const unsigned short* gw = Wt + (size_t)(m0 + grow) * K + gcol;

  const int rg = (l15 & 7);                      // read-side swizzle key

  f32x4 acc[4][4];
#pragma unroll
  for (int i = 0; i < 4; i++)
#pragma unroll
    for (int j = 0; j < 4; j++) acc[i][j] = (f32x4){0.f, 0.f, 0.f, 0.f};

  for (int k0 = 0; k0 < K; k0 += 64) {
    __syncthreads();
#pragma unroll
    for (int t = 0; t < 4; t++) {
      __builtin_amdgcn_global_load_lds((const AS1 void*)(gx + (size_t)t * 8 * ldx + k0),
                                       (AS3 void*)&Xs[w * 2048 + t * 512], 16, 0, 0);
      __builtin_amdgcn_global_load_lds((const AS1 void*)(gw + (size_t)t * 8 * K + k0),
                                       (AS3 void*)&Ws[w * 2048 + t * 512], 16, 0, 0);
    }
    __syncthreads();

#pragma unroll
    for (int ks = 0; ks < 2; ks++) {
      const int gsel = ((ks * 4 + quad) ^ rg) * 8;
      bf16x8 af[4], bf[4];
#pragma unroll
      for (int t = 0; t < 4; t++) {
        af[t] = *(const bf16x8*)&Xs[(wn + t * 16 + l15) * 64 + gsel];
        bf[t] = *(const bf16x8*)&Ws[(wm + t * 16 + l15) * 64 + gsel];
      }
#pragma unroll
      for (int i = 0; i < 4; i++)
#pragma unroll
        for (int j = 0; j < 4; j++)
          acc[i][j] = __builtin_amdgcn_mfma_f32_16x16x32_bf16(af[i], bf[j], acc[i][j], 0, 0, 0);
    }
  }

  // ---- epilogue; D mapping: col=lane&15 (feature), row=(lane>>4)*4+reg ----
  if (mode == 4) {
    // per-lane gating: acc[i][0..3] = (gr, gi, ur, ui) for feature T
    int T = ((m0 + wm) >> 6) * 16 + l15;
#pragma unroll
    for (int i = 0; i < 4; ++i) {
      int row0 = n0 + wn + i * 16 + quad * 4;
#pragma unroll
      for (int r = 0; r < 4; ++r) {
        float gr = acc[i][0][r], gi = acc[i][1][r];
        float ur = acc[i][2][r], ui = acc[i][3][r];
        float sg = 1.f / (1.f + __expf(-sqrtf(gr * gr + gi * gi)));
        float gar = gr * sg, gai = gi * sg;
        unsigned int pk = (unsigned)f2bf(gar * ur - gai * ui)
                        | ((unsigned)f2bf(gar * ui + gai * ur) << 16);
        *(unsigned int*)&outb[(size_t)(row0 + r) * ldo + 2 * T] = pk;
      }
    }
  } else if (mode == 3 && m0 < 2048) {
    // q/k: bias + fused RoPE + direct stores
#pragma unroll
    for (int j = 0; j < 4; ++j) {
      float bv = bias[m0 + wm + j * 16 + l15];
#pragma unroll
      for (int i = 0; i < 4; ++i)
#pragma unroll
        for (int r = 0; r < 4; ++r) acc[i][j][r] += bv;
    }
#pragma unroll
    for (int j01 = 0; j01 < 2; ++j01) {
      float fi = (float)(j01 * 16 + l15);
      float invf = __expf(fi * -0.28782313662425572f);  // -ln(10000)/32
#pragma unroll
      for (int i = 0; i < 4; ++i) {
        int tok0 = n0 + wn + i * 16 + quad * 4;
#pragma unroll
        for (int r = 0; r < 4; ++r) {
          int s = (tok0 + r) & (kS - 1);
          float sn, cs;
          __sincosf((float)s * invf, &sn, &cs);
          float x0 = acc[i][j01][r], x1 = acc[i][j01 + 2][r];
          acc[i][j01][r] = x0 * cs - x1 * sn;
          acc[i][j01 + 2][r] = x1 * cs + x0 * sn;
        }
      }
    }
#pragma unroll
    for (int j = 0; j < 4; ++j) {
      int col = m0 + wm + j * 16 + l15;
#pragma unroll
      for (int i = 0; i < 4; ++i) {
        int row0 = n0 + wn + i * 16 + quad * 4;
#pragma unroll
        for (int r = 0; r < 4; ++r)
          outb[(size_t)(row0 + r) * ldo + col] = f2bf(acc[i][j][r]);
      }
    }
  } else {
    // V: LDS-staged transpose, two wave-parity passes. Ts = 64 x 130 shorts.
    unsigned short* Ts = Sh;
#pragma unroll
    for (int p = 0; p < 2; ++p) {
      __syncthreads();
      if ((w & 1) == p) {
#pragma unroll
        for (int j = 0; j < 4; ++j) {
          float bv = bias[m0 + wm + j * 16 + l15];
          int fl = j * 16 + l15;
#pragma unroll
          for (int i = 0; i < 4; ++i) {
            int tk = wn + i * 16 + quad * 4;
#pragma unroll
            for (int r = 0; r < 4; ++r)
              Ts[fl * 130 + tk + r] = f2bf(acc[i][j][r] + bv);
          }
        }
      }
      __syncthreads();
      {
        int fr = tid >> 2, seg = tid & 3;
        int f = (m0 - 2048) + p * 64 + fr;
        int hh = f >> 7, dc = f & 127;
        int bb = n0 >> 10, sbase = (n0 & (kS - 1)) + seg * 32;
        unsigned short* dst = &vtb[(size_t)((bb * 8 + hh) * 128 + dc) * 1024 + sbase];
        const unsigned short* src = &Ts[fr * 130 + seg * 32];
#pragma unroll
        for (int u = 0; u < 4; u++)
          *(bf16x8*)(dst + u * 8) = *(const bf16x8*)(src + u * 8);
      }
    }
  }
}

// ---------------------------------------------------------------------------
// bf16 MFMA GEMM, 64x128 tile (N=64), BK=64, 4 waves (2n x 2m of 32x64).
// fp32 epilogues only:
//   1: O-proj: outf (N,1024) = acc + bias + x residual (resr/resi stride 512)
//   2: down:   d_out split halves = acc + resr[row*1024+col]
// ---------------------------------------------------------------------------
__global__ __launch_bounds__(256) void cgemm_mfma_n64_kernel(
    const unsigned short* __restrict__ X, int ldx,
    const unsigned short* __restrict__ Wt, int K,
    const float* __restrict__ bias, int mode,
    const float* __restrict__ resr, const float* __restrict__ resi,
    float* __restrict__ outf) {
  __shared__ unsigned short Xs[64 * 64];
  __shared__ unsigned short Ws[128 * 64];

  const int tid = threadIdx.x;
  const int w = tid >> 6;
  const int lane = tid & 63;
  const int quad = lane >> 4;
  const int l15 = lane & 15;
  const int m0 = blockIdx.x * 128;
  const int n0 = blockIdx.y * 64;
  const int wm = (w & 1) * 64;
  const int wn = (w >> 1) * 32;

  const int rsub = lane >> 3;
  const int gcol = ((lane & 7) ^ rsub) * 8;
  const unsigned short* gx = X + (size_t)(n0 + w * 16 + rsub) * ldx + gcol;
  const unsigned short* gw = Wt + (size_t)(m0 + w * 32 + rsub) * K + gcol;
  const int rg = (l15 & 7);

  f32x4 acc[2][4];
#pragma unroll
  for (int i = 0; i < 2; i++)
#pragma unroll
    for (int j = 0; j < 4; j++) acc[i][j] = (f32x4){0.f, 0.f, 0.f, 0.f};

  for (int k0 = 0; k0 < K; k0 += 64) {
    __syncthreads();
#pragma unroll
    for (int t = 0; t < 2; t++)
      __builtin_amdgcn_global_load_lds((const AS1 void*)(gx + (size_t)t * 8 * ldx + k0),
                                       (AS3 void*)&Xs[w * 1024 + t * 512], 16, 0, 0);
#pragma unroll
    for (int t = 0; t < 4; t++)
      __builtin_amdgcn_global_load_lds((const AS1 void*)(gw + (size_t)t * 8 * K + k0),
                                       (AS3 void*)&Ws[w * 2048 + t * 512], 16, 0, 0);
    __syncthreads();

#pragma unroll
    for (int ks = 0; ks < 2; ks++) {
      const int gsel = ((ks * 4 + quad) ^ rg) * 8;
      bf16x8 af[2], bf[4];
#pragma unroll
      for (int t = 0; t < 2; t++)
        af[t] = *(const bf16x8*)&Xs[(wn + t * 16 + l15) * 64 + gsel];
#pragma unroll
      for (int t = 0; t < 4; t++)
        bf[t] = *(const bf16x8*)&Ws[(wm + t * 16 + l15) * 64 + gsel];
#pragma unroll
      for (int i = 0; i < 2; i++)
#pragma unroll
        for (int j = 0; j < 4; j++)
          acc[i][j] = __builtin_amdgcn_mfma_f32_16x16x32_bf16(af[i], bf[j], acc[i][j], 0, 0, 0);
    }
  }

#pragma unroll
  for (int j = 0; j < 4; ++j) {
    int col = m0 + wm + j * 16 + l15;
    float bv = bias ? bias[col] : 0.f;
#pragma unroll
    for (int i = 0; i < 2; ++i) {
      int row0 = n0 + wn + i * 16 + quad * 4;
#pragma unroll
      for (int r = 0; r < 4; ++r) {
        int row = row0 + r;
        float val = acc[i][j][r] + bv;
        if (mode == 1) {
          float xres = (col < 512) ? resr[(size_t)row * 512 + col]
                                   : resi[(size_t)row * 512 + col - 512];
          outf[(size_t)row * 1024 + col] = val + xres;
        } else {
          float rv = resr[(size_t)row * 1024 + col] + val;
          size_t dd = (col < 512) ? ((size_t)row * 512 + col)
                                  : ((size_t)kBSD + (size_t)row * 512 + (col - 512));
          outf[dd] = rv;
        }
      }
    }
  }
}

// ---------------------------------------------------------------------------
// MFMA flash attention (causal, Hermitian). Unchanged from R3/R5 (works).
// ---------------------------------------------------------------------------
__global__ __launch_bounds__(256) void attn_mfma_kernel(
    const unsigned short* __restrict__ qkv,   // (4096, 3072)
    const unsigned short* __restrict__ vt,    // (4,8,128,1024)
    unsigned short* __restrict__ out) {       // (4096, 1024) [ar|ai]
  __shared__ unsigned short Ks[32 * 136];
  __shared__ unsigned short Vs[128 * 40];
  __shared__ unsigned short Ps[4 * 16 * 40];

  const int tid = threadIdx.x;
  const int w = tid >> 6;
  const int lane = tid & 63;
  const int quad = lane >> 4;
  const int l15 = lane & 15;

  int bid = blockIdx.x;
  int qt = bid & 15;
  if ((bid >> 4) & 1) qt = 15 - qt;
  const int h = (bid >> 4) & 7;
  const int b = bid >> 7;
  const int q0 = qt * 64;
  const int wrow0 = q0 + w * 16;

  bf16x8 qa[4];
  {
    size_t base = (size_t)(b * kS + wrow0 + l15) * 3072 + h * 128;
#pragma unroll
    for (int ks = 0; ks < 4; ks++)
      qa[ks] = *(const bf16x8*)&qkv[base + ks * 32 + quad * 8];
  }

  f32x4 oacc[8];
#pragma unroll
  for (int dt = 0; dt < 8; dt++) oacc[dt] = (f32x4){0.f, 0.f, 0.f, 0.f};
  float m_r[4] = {-1e30f, -1e30f, -1e30f, -1e30f};
  float l_r[4] = {0.f, 0.f, 0.f, 0.f};

  const int ktmax_blk = (q0 + 63) >> 5;
  const int ktmax_wav = (wrow0 + 15) >> 5;
  const float cexp = 0.1803368801f;  // (1/sqrt(64)) * log2(e)

  const unsigned short* gkbase = qkv + 1024 + h * 128;
  const unsigned short* gvbase = vt + (size_t)((b * 8 + h) * 128) * 1024;

  for (int kt = 0; kt <= ktmax_blk; ++kt) {
    const int k0 = kt * 32;
    __syncthreads();
    {
      int ch = tid * 2;
      int r = ch >> 4, cc = (ch & 15) * 8;
      const unsigned short* gk = gkbase + (size_t)(b * kS + k0) * 3072;
      *(bf16x8*)&Ks[r * 136 + cc] = *(const bf16x8*)&gk[(size_t)r * 3072 + cc];
      int r2 = (ch + 1) >> 4, cc2 = ((ch + 1) & 15) * 8;
      *(bf16x8*)&Ks[r2 * 136 + cc2] = *(const bf16x8*)&gk[(size_t)r2 * 3072 + cc2];
      int vr = ch >> 2, vc = (ch & 3) * 8;
      *(bf16x8*)&Vs[vr * 40 + vc] = *(const bf16x8*)&gvbase[(size_t)vr * 1024 + k0 + vc];
      int vr2 = (ch + 1) >> 2, vc2 = ((ch + 1) & 3) * 8;
      *(bf16x8*)&Vs[vr2 * 40 + vc2] = *(const bf16x8*)&gvbase[(size_t)vr2 * 1024 + k0 + vc2];
    }
    __syncthreads();

    if (kt <= ktmax_wav) {
      f32x4 s[2];
      s[0] = (f32x4){0.f, 0.f, 0.f, 0.f};
      s[1] = (f32x4){0.f, 0.f, 0.f, 0.f};
#pragma unroll
      for (int ns = 0; ns < 2; ns++)
#pragma unroll
        for (int ks = 0; ks < 4; ks++) {
          bf16x8 kb = *(const bf16x8*)&Ks[(ns * 16 + l15) * 136 + ks * 32 + quad * 8];
          s[ns] = __builtin_amdgcn_mfma_f32_16x16x32_bf16(qa[ks], kb, s[ns], 0, 0, 0);
        }

      if (k0 + 31 > wrow0) {
#pragma unroll
        for (int r = 0; r < 4; r++) {
          int qrow = wrow0 + quad * 4 + r;
          if (k0 + l15 > qrow) s[0][r] = -1e30f;
          if (k0 + 16 + l15 > qrow) s[1][r] = -1e30f;
        }
      }

      float alpha[4];
#pragma unroll
      for (int r = 0; r < 4; r++) {
        float mx = fmaxf(s[0][r], s[1][r]);
        mx = fmaxf(mx, __shfl_xor(mx, 1));
        mx = fmaxf(mx, __shfl_xor(mx, 2));
        mx = fmaxf(mx, __shfl_xor(mx, 4));
        mx = fmaxf(mx, __shfl_xor(mx, 8));
        float mn = fmaxf(m_r[r], mx);
        float al = exp2f((m_r[r] - mn) * cexp);
        m_r[r] = mn;
        float p0 = exp2f((s[0][r] - mn) * cexp);
        float p1 = exp2f((s[1][r] - mn) * cexp);
        s[0][r] = p0;
        s[1][r] = p1;
        float rs = p0 + p1;
        rs += __shfl_xor(rs, 1);
        rs += __shfl_xor(rs, 2);
        rs += __shfl_xor(rs, 4);
        rs += __shfl_xor(rs, 8);
        l_r[r] = l_r[r] * al + rs;
        alpha[r] = al;
      }

#pragma unroll
      for (int dt = 0; dt < 8; dt++)
#pragma unroll
        for (int r = 0; r < 4; r++) oacc[dt][r] *= alpha[r];

      unsigned short* pw = &Ps[w * 640];
#pragma unroll
      for (int r = 0; r < 4; r++) {
        int q = quad * 4 + r;
        pw[q * 40 + l15] = f2bf(s[0][r]);
        pw[q * 40 + 16 + l15] = f2bf(s[1][r]);
      }
      bf16x8 pa = *(const bf16x8*)&pw[l15 * 40 + quad * 8];

#pragma unroll
      for (int dt = 0; dt < 8; dt++) {
        bf16x8 vb = *(const bf16x8*)&Vs[(dt * 16 + l15) * 40 + quad * 8];
        oacc[dt] = __builtin_amdgcn_mfma_f32_16x16x32_bf16(pa, vb, oacc[dt], 0, 0, 0);
      }
    }
  }

  float inv[4];
#pragma unroll
  for (int r = 0; r < 4; r++) inv[r] = 1.f / l_r[r];
#pragma unroll
  for (int dt = 0; dt < 8; dt++) {
    int dcat = dt * 16 + l15;
    int col = (dcat < 64) ? (h * 64 + dcat) : (512 + h * 64 + dcat - 64);
#pragma unroll
    for (int r = 0; r < 4; r++) {
      int tok = b * kS + wrow0 + quad * 4 + r;
      out[(size_t)tok * 1024 + col] = f2bf(oacc[dt][r] * inv[r]);
    }
  }
}

// ---------------------------------------------------------------------------
// Launcher
// ---------------------------------------------------------------------------
extern "C" void kernel_launch(void* const* d_in, const int* in_sizes, int n_in,
                              void* d_out, int out_size, void* d_ws, size_t ws_size,
                              hipStream_t stream) {
  const float* x_real = (const float*)d_in[0];
  const float* x_imag = (const float*)d_in[1];
  const float* ln1_gr = (const float*)d_in[2];
  const float* ln1_gi = (const float*)d_in[3];
  const float* ln1_br = (const float*)d_in[4];
  const float* ln1_bi = (const float*)d_in[5];
  const float* q_lm = (const float*)d_in[6];
  const float* q_ph = (const float*)d_in[7];
  const float* q_bm = (const float*)d_in[8];
  const float* q_bp = (const float*)d_in[9];
  const float* k_lm = (const float*)d_in[10];
  const float* k_ph = (const float*)d_in[11];
  const float* k_bm = (const float*)d_in[12];
  const float* k_bp = (const float*)d_in[13];
  const float* v_lm = (const float*)d_in[14];
  const float* v_ph = (const float*)d_in[15];
  const float* v_bm = (const float*)d_in[16];
  const float* v_bp = (const float*)d_in[17];
  const float* o_lm = (const float*)d_in[18];
  const float* o_ph = (const float*)d_in[19];
  const float* o_bm = (const float*)d_in[20];
  const float* o_bp = (const float*)d_in[21];
  const float* ln2_gr = (const float*)d_in[22];
  const float* ln2_gi = (const float*)d_in[23];
  const float* ln2_br = (const float*)d_in[24];
  const float* ln2_bi = (const float*)d_in[25];
  const float* gate_lm = (const float*)d_in[26];
  const float* gate_ph = (const float*)d_in[27];
  const float* up_lm = (const float*)d_in[28];
  const float* up_ph = (const float*)d_in[29];
  const float* down_lm = (const float*)d_in[30];
  const float* down_ph = (const float*)d_in[31];

  // ---- workspace layout (bytes) ----
  char* wsb = (char*)d_ws;
  unsigned short* Wqkv = (unsigned short*)(wsb + 0);           // 3072x1024 bf16
  unsigned short* Wo   = (unsigned short*)(wsb + 6291456);     // 1024x1024
  unsigned short* Wgu  = (unsigned short*)(wsb + 8388608);     // 8192x1024 (role-in-j)
  unsigned short* Wd   = (unsigned short*)(wsb + 25165824);    // 1024x4096 (interleaved K)
  float* qkvBias = (float*)(wsb + 33554432);                   // 3072 fp32
  float* oBias   = (float*)(wsb + 33566720);                   // 1024 fp32
  float* res     = (float*)(wsb + 33570816);                   // 4096x1024 fp32
  unsigned short* H = (unsigned short*)(wsb + 50348032);       // 4096x1024 bf16
  char* big = wsb + 58736640;
  unsigned short* qkv     = (unsigned short*)big;              // 4096x3072 bf16
  unsigned short* attnout = (unsigned short*)(big + 25165824); // 4096x1024 bf16
  unsigned short* vtb     = (unsigned short*)(big + 33554432); // 4x8x128x1024 bf16
  unsigned short* hid     = (unsigned short*)big;              // 4096x4096 bf16 (aliases dead bufs)

  float* outf = (float*)d_out;  // (2, 4096, 512)

  // 1) fused builds
  build_wA_kernel<<<4096, 256, 0, stream>>>(q_lm, q_ph, k_lm, k_ph, v_lm, v_ph,
                                            o_lm, o_ph, Wqkv, Wo);
  build_wB_kernel<<<12288, 256, 0, stream>>>(gate_lm, gate_ph, up_lm, up_ph,
                                             down_lm, down_ph, Wgu, Wd);
  build_bias_all_kernel<<<8, 256, 0, stream>>>(q_bm, q_bp, k_bm, k_bp, v_bm, v_bp,
                                               o_bm, o_bp, qkvBias, oBias);

  // 2) LN1: x -> H
  cln_kernel<<<kNT / 4, 256, 0, stream>>>(x_real, x_imag, 512, ln1_gr, ln1_gi, ln1_br, ln1_bi, H);

  // 3) QKV fused GEMM (mode 3): rope fused for q/k, V transposed to vtb
  {
    dim3 g(3072 / 128, kNT / 128);
    cgemm_mfma_kernel<<<g, 256, 0, stream>>>(H, 1024, Wqkv, 1024, qkvBias, 3, qkv, 3072, vtb);
  }

  // 4) attention -> attnout
  attn_mfma_kernel<<<kB * kH * (kS / 64), 256, 0, stream>>>(qkv, vtb, attnout);

  // 5) O-proj + x residual -> res fp32
  {
    dim3 g(1024 / 128, kNT / 64);
    cgemm_mfma_n64_kernel<<<g, 256, 0, stream>>>(attnout, 1024, Wo, 1024, oBias, 1,
                                                 x_real, x_imag, res);
  }

  // 6) LN2: res -> H
  cln_kernel<<<kNT / 4, 256, 0, stream>>>(res, res + 512, 1024, ln2_gr, ln2_gi, ln2_br, ln2_bi, H);

  // 7) gate+up GEMM with per-lane fused gating (mode 4) -> hid (N,4096)
  {
    dim3 g(8192 / 128, kNT / 128);
    cgemm_mfma_kernel<<<g, 256, 0, stream>>>(H, 1024, Wgu, 1024, nullptr, 4, hid, 4096, nullptr);
  }

  // 8) down GEMM + residual -> d_out
  {
    dim3 g(1024 / 128, kNT / 64);
    cgemm_mfma_n64_kernel<<<g, 256, 0, stream>>>(hid, 4096, Wd, 4096, nullptr, 2,
                                                 res, nullptr, outf);
  }
}

// Round 7
// 433.469 us; speedup vs baseline: 1.3732x; 1.0640x over previous
//
#include <hip/hip_runtime.h>
#include <math.h>

// Problem constants: B=4, S=1024, D=512, H=8, HD=64, HID=2048
#define kB 4
#define kS 1024
#define kD 512
#define kH 8
#define kHD 64
#define kHID 2048
#define kNT (kB * kS)          // 4096 tokens
#define kBSD (kNT * kD)        // 2,097,152

typedef __attribute__((ext_vector_type(8))) short bf16x8;
typedef __attribute__((ext_vector_type(4))) float f32x4;

#define AS1 __attribute__((address_space(1)))
#define AS3 __attribute__((address_space(3)))

__device__ __forceinline__ float bf2f(unsigned short u) {
  return __uint_as_float(((unsigned int)u) << 16);
}
__device__ __forceinline__ unsigned short f2bf(float f) {
  unsigned int u = __float_as_uint(f);
  u += 0x7fffu + ((u >> 16) & 1u);   // RNE
  return (unsigned short)(u >> 16);
}

// ---------------------------------------------------------------------------
// Fused weight build A: QKV (head-permuted) + O (standard cat) + all biases.
// grid 4104 x 256. Blocks <4096: seg = gid>>18: 0=q,1=k,2=v (perm), 3=o (std).
// Blocks >=4096: bias build (2048 threads over 4 segments).
// ---------------------------------------------------------------------------
__global__ __launch_bounds__(256) void build_wA_kernel(
    const float* __restrict__ qlm, const float* __restrict__ qph,
    const float* __restrict__ klm, const float* __restrict__ kph,
    const float* __restrict__ vlm, const float* __restrict__ vph,
    const float* __restrict__ olm, const float* __restrict__ oph,
    const float* __restrict__ qbm, const float* __restrict__ qbp,
    const float* __restrict__ kbm, const float* __restrict__ kbp,
    const float* __restrict__ vbm, const float* __restrict__ vbp,
    const float* __restrict__ obm, const float* __restrict__ obp,
    unsigned short* __restrict__ Wqkv, unsigned short* __restrict__ Wo,
    float* __restrict__ qkvBias, float* __restrict__ oBias) {
  int bx = blockIdx.x;
  if (bx >= 4096) {
    int gid = (bx - 4096) * 256 + threadIdx.x;  // 0..2047
    int seg = gid >> 9, m = gid & 511;
    const float* bm = seg == 0 ? qbm : seg == 1 ? kbm : seg == 2 ? vbm : obm;
    const float* bp = seg == 0 ? qbp : seg == 1 ? kbp : seg == 2 ? vbp : obp;
    float s, c;
    __sincosf(bp[m], &s, &c);
    float br = bm[m] * c, bi = bm[m] * s;
    if (seg < 3) {
      int h = m >> 6, d = m & 63;
      qkvBias[seg * 1024 + h * 128 + d] = br;
      qkvBias[seg * 1024 + h * 128 + 64 + d] = bi;
    } else {
      oBias[m] = br;
      oBias[512 + m] = bi;
    }
    return;
  }
  int gid = bx * 256 + threadIdx.x;
  int seg = gid >> 18;
  int id = gid & 262143;
  const float* lm = seg == 0 ? qlm : seg == 1 ? klm : seg == 2 ? vlm : olm;
  const float* ph = seg == 0 ? qph : seg == 1 ? kph : seg == 2 ? vph : oph;
  float mm = __expf(lm[id]);
  float s, c;
  __sincosf(ph[id], &s, &c);
  float wr = mm * c, wi = mm * s;
  int m = id >> 9, k = id & 511;
  if (seg < 3) {
    int h = m >> 6, d = m & 63;
    size_t rowR = (size_t)seg * 1024 + h * 128 + d;
    size_t rowI = rowR + 64;
    Wqkv[rowR * 1024 + k] = f2bf(wr);
    Wqkv[rowR * 1024 + 512 + k] = f2bf(-wi);
    Wqkv[rowI * 1024 + k] = f2bf(wi);
    Wqkv[rowI * 1024 + 512 + k] = f2bf(wr);
  } else {
    Wo[(size_t)m * 1024 + k] = f2bf(wr);
    Wo[(size_t)m * 1024 + 512 + k] = f2bf(-wi);
    Wo[(size_t)(512 + m) * 1024 + k] = f2bf(wi);
    Wo[(size_t)(512 + m) * 1024 + 512 + k] = f2bf(wr);
  }
}

// ---------------------------------------------------------------------------
// Fused weight build B.
// Wgu role-in-j layout: feature T (0..2047) lives in 64-row group g=T>>4 at
// row = g*64 + role*16 + (T&15), roles: 0=gate_r,1=gate_i,2=up_r,3=up_i.
// Wd: K interleaved as pairs 2j,2j+1 = (hr,hi).
// grid 12288 x 256. seg = gid>>20: 0=gate,1=up,2=down.
// ---------------------------------------------------------------------------
__global__ __launch_bounds__(256) void build_wB_kernel(
    const float* __restrict__ glm, const float* __restrict__ gph,
    const float* __restrict__ ulm, const float* __restrict__ uph,
    const float* __restrict__ dlm, const float* __restrict__ dph,
    unsigned short* __restrict__ Wgu, unsigned short* __restrict__ Wd) {
  int gid = blockIdx.x * 256 + threadIdx.x;
  int seg = gid >> 20;
  int id = gid & 1048575;
  const float* lm = seg == 0 ? glm : seg == 1 ? ulm : dlm;
  const float* ph = seg == 0 ? gph : seg == 1 ? uph : dph;
  float mm = __expf(lm[id]);
  float s, c;
  __sincosf(ph[id], &s, &c);
  float wr = mm * c, wi = mm * s;
  if (seg < 2) {
    int T = id >> 9, k = id & 511;
    size_t base = (size_t)(T >> 4) * 64 + (T & 15);
    size_t rR = base + (seg * 2 + 0) * 16;   // gate->role0, up->role2
    size_t rI = base + (seg * 2 + 1) * 16;   // gate->role1, up->role3
    Wgu[rR * 1024 + k] = f2bf(wr);
    Wgu[rR * 1024 + 512 + k] = f2bf(-wi);
    Wgu[rI * 1024 + k] = f2bf(wi);
    Wgu[rI * 1024 + 512 + k] = f2bf(wr);
  } else {
    int m = id >> 11, j = id & 2047;
    Wd[(size_t)m * 4096 + 2 * j] = f2bf(wr);
    Wd[(size_t)m * 4096 + 2 * j + 1] = f2bf(-wi);
    Wd[(size_t)(512 + m) * 4096 + 2 * j] = f2bf(wi);
    Wd[(size_t)(512 + m) * 4096 + 2 * j + 1] = f2bf(wr);
  }
}

// ---------------------------------------------------------------------------
// Complex LayerNorm: one WAVE per token, shfl butterflies, no barriers.
// fp32 in (row stride) -> bf16 (N,1024) [r|i]. grid = NT/4.
// ---------------------------------------------------------------------------
__global__ __launch_bounds__(256) void cln_kernel(
    const float* __restrict__ xr, const float* __restrict__ xi, int stride,
    const float* __restrict__ g_r, const float* __restrict__ g_i,
    const float* __restrict__ b_r, const float* __restrict__ b_i,
    unsigned short* __restrict__ out) {
  int w = threadIdx.x >> 6, lane = threadIdx.x & 63;
  int t = blockIdx.x * 4 + w;
  int d0 = lane * 8;
  const float* xrt = xr + (size_t)t * stride + d0;
  const float* xit = xi + (size_t)t * stride + d0;
  float4 a0 = *(const float4*)&xrt[0];
  float4 a1 = *(const float4*)&xrt[4];
  float4 c0 = *(const float4*)&xit[0];
  float4 c1 = *(const float4*)&xit[4];

  float s1 = a0.x + a0.y + a0.z + a0.w + a1.x + a1.y + a1.z + a1.w;
  float s2 = c0.x + c0.y + c0.z + c0.w + c1.x + c1.y + c1.z + c1.w;
#pragma unroll
  for (int off = 1; off < 64; off <<= 1) {
    s1 += __shfl_xor(s1, off);
    s2 += __shfl_xor(s2, off);
  }
  float mr = s1 * (1.f / kD), mi = s2 * (1.f / kD);

  float ar[8] = {a0.x, a0.y, a0.z, a0.w, a1.x, a1.y, a1.z, a1.w};
  float ai[8] = {c0.x, c0.y, c0.z, c0.w, c1.x, c1.y, c1.z, c1.w};
  float v = 0.f;
#pragma unroll
  for (int e = 0; e < 8; e++) {
    float cr = ar[e] - mr, ci = ai[e] - mi;
    v += cr * cr + ci * ci;
  }
#pragma unroll
  for (int off = 1; off < 64; off <<= 1) v += __shfl_xor(v, off);
  float inv = rsqrtf(v * (1.f / kD) + 1e-6f);

  float4 g0 = *(const float4*)&g_r[d0];
  float4 g1 = *(const float4*)&g_r[d0 + 4];
  float4 h0 = *(const float4*)&g_i[d0];
  float4 h1 = *(const float4*)&g_i[d0 + 4];
  float4 p0 = *(const float4*)&b_r[d0];
  float4 p1 = *(const float4*)&b_r[d0 + 4];
  float4 q0 = *(const float4*)&b_i[d0];
  float4 q1 = *(const float4*)&b_i[d0 + 4];
  float gr[8] = {g0.x, g0.y, g0.z, g0.w, g1.x, g1.y, g1.z, g1.w};
  float gi[8] = {h0.x, h0.y, h0.z, h0.w, h1.x, h1.y, h1.z, h1.w};
  float br[8] = {p0.x, p0.y, p0.z, p0.w, p1.x, p1.y, p1.z, p1.w};
  float bi[8] = {q0.x, q0.y, q0.z, q0.w, q1.x, q1.y, q1.z, q1.w};

  unsigned short pr[8], pi[8];
#pragma unroll
  for (int e = 0; e < 8; e++) {
    float nr = (ar[e] - mr) * inv;
    float ni = (ai[e] - mi) * inv;
    pr[e] = f2bf(nr * gr[e] - ni * gi[e] + br[e]);
    pi[e] = f2bf(nr * gi[e] + ni * gr[e] + bi[e]);
  }
  unsigned short* ot = out + (size_t)t * 1024 + d0;
  *(bf16x8*)&ot[0] = *(const bf16x8*)pr;
  *(bf16x8*)&ot[512] = *(const bf16x8*)pi;
}

// ---------------------------------------------------------------------------
// bf16 MFMA GEMM, 128x128 tile, BK=64, 4 waves, 16x16x32 MFMA.
// XOR-swizzled staging (0 bank conflicts).
// Epilogue modes:
//   3: QKV: q/k blocks (m0<2048) -> bias + FUSED ROPE (angle-addition) +
//      direct bf16 stores (ldo=3072); V blocks -> bias + LDS-staged
//      transpose to vt[b][h][dcat][s]
//   4: gateup: roles along j (0=gr,1=gi,2=ur,3=ui); per-lane gating, packed
//      (hr,hi) 4B store to hid (N,4096)
// ---------------------------------------------------------------------------
__global__ __launch_bounds__(256) void cgemm_mfma_kernel(
    const unsigned short* __restrict__ X, int ldx,
    const unsigned short* __restrict__ Wt, int K,
    const float* __restrict__ bias, int mode,
    unsigned short* __restrict__ outb, int ldo,
    unsigned short* __restrict__ vtb) {
  __shared__ unsigned short Sh[128 * 64 * 2];   // Xs | Ws, 32 KB
  unsigned short* Xs = Sh;
  unsigned short* Ws = Sh + 8192;

  const int tid = threadIdx.x;
  const int w = tid >> 6;
  const int lane = tid & 63;
  const int quad = lane >> 4;
  const int l15 = lane & 15;
  const int m0 = blockIdx.x * 128;
  const int n0 = blockIdx.y * 128;
  const int wm = (w & 1) * 64;
  const int wn = (w >> 1) * 64;

  const int rsub = lane >> 3;                    // 0..7
  const int grow = w * 32 + rsub;                // + t*8 per inst
  const int gcol = ((lane & 7) ^ rsub) * 8;      // swizzled global granule
  const unsigned short* gx = X + (size_t)(n0 + grow) * ldx + gcol;
  const unsigned short* gw = Wt + (size_t)(m0 + grow) * K + gcol;

  const int rg = (l15 & 7);                      // read-side swizzle key

  f32x4 acc[4][4];
#pragma unroll
  for (int i = 0; i < 4; i++)
#pragma unroll
    for (int j = 0; j < 4; j++) acc[i][j] = (f32x4){0.f, 0.f, 0.f, 0.f};

  for (int k0 = 0; k0 < K; k0 += 64) {
    __syncthreads();
#pragma unroll
    for (int t = 0; t < 4; t++) {
      __builtin_amdgcn_global_load_lds((const AS1 void*)(gx + (size_t)t * 8 * ldx + k0),
                                       (AS3 void*)&Xs[w * 2048 + t * 512], 16, 0, 0);
      __builtin_amdgcn_global_load_lds((const AS1 void*)(gw + (size_t)t * 8 * K + k0),
                                       (AS3 void*)&Ws[w * 2048 + t * 512], 16, 0, 0);
    }
    __syncthreads();

#pragma unroll
    for (int ks = 0; ks < 2; ks++) {
      const int gsel = ((ks * 4 + quad) ^ rg) * 8;
      bf16x8 af[4], bf[4];
#pragma unroll
      for (int t = 0; t < 4; t++) {
        af[t] = *(const bf16x8*)&Xs[(wn + t * 16 + l15) * 64 + gsel];
        bf[t] = *(const bf16x8*)&Ws[(wm + t * 16 + l15) * 64 + gsel];
      }
#pragma unroll
      for (int i = 0; i < 4; i++)
#pragma unroll
        for (int j = 0; j < 4; j++)
          acc[i][j] = __builtin_amdgcn_mfma_f32_16x16x32_bf16(af[i], bf[j], acc[i][j], 0, 0, 0);
    }
  }

  // ---- epilogue; D mapping: col=lane&15 (feature), row=(lane>>4)*4+reg ----
  if (mode == 4) {
    // per-lane gating: acc[i][0..3] = (gr, gi, ur, ui) for feature T
    int T = ((m0 + wm) >> 6) * 16 + l15;
#pragma unroll
    for (int i = 0; i < 4; ++i) {
      int row0 = n0 + wn + i * 16 + quad * 4;
#pragma unroll
      for (int r = 0; r < 4; ++r) {
        float gr = acc[i][0][r], gi = acc[i][1][r];
        float ur = acc[i][2][r], ui = acc[i][3][r];
        float sg = __builtin_amdgcn_rcpf(1.f + __expf(-sqrtf(gr * gr + gi * gi)));
        float gar = gr * sg, gai = gi * sg;
        unsigned int pk = (unsigned)f2bf(gar * ur - gai * ui)
                        | ((unsigned)f2bf(gar * ui + gai * ur) << 16);
        *(unsigned int*)&outb[(size_t)(row0 + r) * ldo + 2 * T] = pk;
      }
    }
  } else if (mode == 3 && m0 < 2048) {
    // q/k: bias + fused RoPE (angle-addition: 6 sincos instead of 32)
#pragma unroll
    for (int j = 0; j < 4; ++j) {
      float bv = bias[m0 + wm + j * 16 + l15];
#pragma unroll
      for (int i = 0; i < 4; ++i)
#pragma unroll
        for (int r = 0; r < 4; ++r) acc[i][j][r] += bv;
    }
    const int sbase = ((n0 + wn) & (kS - 1)) + quad * 4;
#pragma unroll
    for (int j01 = 0; j01 < 2; ++j01) {
      float fi = (float)(j01 * 16 + l15);
      float f = __expf(fi * -0.28782313662425572f);  // -ln(10000)/32
      float c1, s1, c16, s16, cI, sI;
      __sincosf(f, &s1, &c1);
      __sincosf(16.f * f, &s16, &c16);
      __sincosf((float)sbase * f, &sI, &cI);
#pragma unroll
      for (int i = 0; i < 4; ++i) {
        float cc = cI, ss = sI;
#pragma unroll
        for (int r = 0; r < 4; ++r) {
          float x0 = acc[i][j01][r], x1 = acc[i][j01 + 2][r];
          acc[i][j01][r] = x0 * cc - x1 * ss;
          acc[i][j01 + 2][r] = x1 * cc + x0 * ss;
          float cn = cc * c1 - ss * s1;           // advance by f
          ss = ss * c1 + cc * s1;
          cc = cn;
        }
        float cn = cI * c16 - sI * s16;           // advance by 16f
        sI = sI * c16 + cI * s16;
        cI = cn;
      }
    }
#pragma unroll
    for (int j = 0; j < 4; ++j) {
      int col = m0 + wm + j * 16 + l15;
#pragma unroll
      for (int i = 0; i < 4; ++i) {
        int row0 = n0 + wn + i * 16 + quad * 4;
#pragma unroll
        for (int r = 0; r < 4; ++r)
          outb[(size_t)(row0 + r) * ldo + col] = f2bf(acc[i][j][r]);
      }
    }
  } else {
    // V: LDS-staged transpose, two wave-parity passes. Ts = 64 x 130 shorts.
    unsigned short* Ts = Sh;
#pragma unroll
    for (int p = 0; p < 2; ++p) {
      __syncthreads();
      if ((w & 1) == p) {
#pragma unroll
        for (int j = 0; j < 4; ++j) {
          float bv = bias[m0 + wm + j * 16 + l15];
          int fl = j * 16 + l15;
#pragma unroll
          for (int i = 0; i < 4; ++i) {
            int tk = wn + i * 16 + quad * 4;
#pragma unroll
            for (int r = 0; r < 4; ++r)
              Ts[fl * 130 + tk + r] = f2bf(acc[i][j][r] + bv);
          }
        }
      }
      __syncthreads();
      {
        int fr = tid >> 2, seg = tid & 3;
        int f = (m0 - 2048) + p * 64 + fr;
        int hh = f >> 7, dc = f & 127;
        int bb = n0 >> 10, sbase2 = (n0 & (kS - 1)) + seg * 32;
        unsigned short* dst = &vtb[(size_t)((bb * 8 + hh) * 128 + dc) * 1024 + sbase2];
        const unsigned short* src = &Ts[fr * 130 + seg * 32];
#pragma unroll
        for (int u = 0; u < 4; u++)
          *(bf16x8*)(dst + u * 8) = *(const bf16x8*)(src + u * 8);
      }
    }
  }
}

// ---------------------------------------------------------------------------
// bf16 MFMA GEMM, 64x128 tile (N=64), BK=64, 4 waves (2n x 2m of 32x64).
// fp32 epilogues only:
//   1: O-proj: outf (N,1024) = acc + bias + x residual (resr/resi stride 512)
//   2: down:   d_out split halves = acc + resr[row*1024+col]
// ---------------------------------------------------------------------------
__global__ __launch_bounds__(256) void cgemm_mfma_n64_kernel(
    const unsigned short* __restrict__ X, int ldx,
    const unsigned short* __restrict__ Wt, int K,
    const float* __restrict__ bias, int mode,
    const float* __restrict__ resr, const float* __restrict__ resi,
    float* __restrict__ outf) {
  __shared__ unsigned short Xs[64 * 64];
  __shared__ unsigned short Ws[128 * 64];

  const int tid = threadIdx.x;
  const int w = tid >> 6;
  const int lane = tid & 63;
  const int quad = lane >> 4;
  const int l15 = lane & 15;
  const int m0 = blockIdx.x * 128;
  const int n0 = blockIdx.y * 64;
  const int wm = (w & 1) * 64;
  const int wn = (w >> 1) * 32;

  const int rsub = lane >> 3;
  const int gcol = ((lane & 7) ^ rsub) * 8;
  const unsigned short* gx = X + (size_t)(n0 + w * 16 + rsub) * ldx + gcol;
  const unsigned short* gw = Wt + (size_t)(m0 + w * 32 + rsub) * K + gcol;
  const int rg = (l15 & 7);

  f32x4 acc[2][4];
#pragma unroll
  for (int i = 0; i < 2; i++)
#pragma unroll
    for (int j = 0; j < 4; j++) acc[i][j] = (f32x4){0.f, 0.f, 0.f, 0.f};

  for (int k0 = 0; k0 < K; k0 += 64) {
    __syncthreads();
#pragma unroll
    for (int t = 0; t < 2; t++)
      __builtin_amdgcn_global_load_lds((const AS1 void*)(gx + (size_t)t * 8 * ldx + k0),
                                       (AS3 void*)&Xs[w * 1024 + t * 512], 16, 0, 0);
#pragma unroll
    for (int t = 0; t < 4; t++)
      __builtin_amdgcn_global_load_lds((const AS1 void*)(gw + (size_t)t * 8 * K + k0),
                                       (AS3 void*)&Ws[w * 2048 + t * 512], 16, 0, 0);
    __syncthreads();

#pragma unroll
    for (int ks = 0; ks < 2; ks++) {
      const int gsel = ((ks * 4 + quad) ^ rg) * 8;
      bf16x8 af[2], bf[4];
#pragma unroll
      for (int t = 0; t < 2; t++)
        af[t] = *(const bf16x8*)&Xs[(wn + t * 16 + l15) * 64 + gsel];
#pragma unroll
      for (int t = 0; t < 4; t++)
        bf[t] = *(const bf16x8*)&Ws[(wm + t * 16 + l15) * 64 + gsel];
#pragma unroll
      for (int i = 0; i < 2; i++)
#pragma unroll
        for (int j = 0; j < 4; j++)
          acc[i][j] = __builtin_amdgcn_mfma_f32_16x16x32_bf16(af[i], bf[j], acc[i][j], 0, 0, 0);
    }
  }

#pragma unroll
  for (int j = 0; j < 4; ++j) {
    int col = m0 + wm + j * 16 + l15;
    float bv = bias ? bias[col] : 0.f;
#pragma unroll
    for (int i = 0; i < 2; ++i) {
      int row0 = n0 + wn + i * 16 + quad * 4;
#pragma unroll
      for (int r = 0; r < 4; ++r) {
        int row = row0 + r;
        float val = acc[i][j][r] + bv;
        if (mode == 1) {
          float xres = (col < 512) ? resr[(size_t)row * 512 + col]
                                   : resi[(size_t)row * 512 + col - 512];
          outf[(size_t)row * 1024 + col] = val + xres;
        } else {
          float rv = resr[(size_t)row * 1024 + col] + val;
          size_t dd = (col < 512) ? ((size_t)row * 512 + col)
                                  : ((size_t)kBSD + (size_t)row * 512 + (col - 512));
          outf[dd] = rv;
        }
      }
    }
  }
}

// ---------------------------------------------------------------------------
// MFMA flash attention (causal, Hermitian). Block = (b,h,64-query tile),
// 4 waves x 16 q-rows. K-tile = 64 keys (halved barrier/softmax count vs 32).
// LDS: Ks 64x136 + Vs 128x72 + Ps 4x16x72 = 45,056 B.
// ---------------------------------------------------------------------------
__global__ __launch_bounds__(256) void attn_mfma_kernel(
    const unsigned short* __restrict__ qkv,   // (4096, 3072)
    const unsigned short* __restrict__ vt,    // (4,8,128,1024)
    unsigned short* __restrict__ out) {       // (4096, 1024) [ar|ai]
  __shared__ unsigned short Ks[64 * 136];
  __shared__ unsigned short Vs[128 * 72];
  __shared__ unsigned short Ps[4 * 16 * 72];

  const int tid = threadIdx.x;
  const int w = tid >> 6;
  const int lane = tid & 63;
  const int quad = lane >> 4;
  const int l15 = lane & 15;

  int bid = blockIdx.x;
  int qt = bid & 15;
  if ((bid >> 4) & 1) qt = 15 - qt;   // alternate heavy/light for balance
  const int h = (bid >> 4) & 7;
  const int b = bid >> 7;
  const int q0 = qt * 64;
  const int wrow0 = q0 + w * 16;

  bf16x8 qa[4];
  {
    size_t base = (size_t)(b * kS + wrow0 + l15) * 3072 + h * 128;
#pragma unroll
    for (int ks = 0; ks < 4; ks++)
      qa[ks] = *(const bf16x8*)&qkv[base + ks * 32 + quad * 8];
  }

  f32x4 oacc[8];
#pragma unroll
  for (int dt = 0; dt < 8; dt++) oacc[dt] = (f32x4){0.f, 0.f, 0.f, 0.f};
  float m_r[4] = {-1e30f, -1e30f, -1e30f, -1e30f};
  float l_r[4] = {0.f, 0.f, 0.f, 0.f};

  const int nkt = qt + 1;
  const float cexp = 0.1803368801f;  // (1/sqrt(64)) * log2(e)

  const unsigned short* gkbase = qkv + 1024 + h * 128;
  const unsigned short* gvbase = vt + (size_t)((b * 8 + h) * 128) * 1024;

  for (int kt = 0; kt < nkt; ++kt) {
    const int k0 = kt * 64;
    __syncthreads();
    {
      // K: 64 rows x 128 shorts = 1024 chunks; V: 128 rows x 64 = 1024 chunks
      const unsigned short* gk = gkbase + (size_t)(b * kS + k0) * 3072;
      int ch = tid * 4;
#pragma unroll
      for (int u = 0; u < 4; u++) {
        int r = (ch + u) >> 4, cc = ((ch + u) & 15) * 8;
        *(bf16x8*)&Ks[r * 136 + cc] = *(const bf16x8*)&gk[(size_t)r * 3072 + cc];
      }
#pragma unroll
      for (int u = 0; u < 4; u++) {
        int vr = (ch + u) >> 3, vc = ((ch + u) & 7) * 8;
        *(bf16x8*)&Vs[vr * 72 + vc] = *(const bf16x8*)&gvbase[(size_t)vr * 1024 + k0 + vc];
      }
    }
    __syncthreads();

    // ---- scores S[16 q][64 keys]: 16 MFMA ----
    f32x4 s[4];
#pragma unroll
    for (int ns = 0; ns < 4; ns++) {
      s[ns] = (f32x4){0.f, 0.f, 0.f, 0.f};
#pragma unroll
      for (int ks = 0; ks < 4; ks++) {
        bf16x8 kb = *(const bf16x8*)&Ks[(ns * 16 + l15) * 136 + ks * 32 + quad * 8];
        s[ns] = __builtin_amdgcn_mfma_f32_16x16x32_bf16(qa[ks], kb, s[ns], 0, 0, 0);
      }
    }

    // ---- causal mask (only on the diagonal tile) ----
    if (k0 + 63 > wrow0) {
#pragma unroll
      for (int r = 0; r < 4; r++) {
        int qrow = wrow0 + quad * 4 + r;
#pragma unroll
        for (int ns = 0; ns < 4; ns++)
          if (k0 + ns * 16 + l15 > qrow) s[ns][r] = -1e30f;
      }
    }

    // ---- online softmax ----
    float alpha[4];
#pragma unroll
    for (int r = 0; r < 4; r++) {
      float mx = fmaxf(fmaxf(s[0][r], s[1][r]), fmaxf(s[2][r], s[3][r]));
      mx = fmaxf(mx, __shfl_xor(mx, 1));
      mx = fmaxf(mx, __shfl_xor(mx, 2));
      mx = fmaxf(mx, __shfl_xor(mx, 4));
      mx = fmaxf(mx, __shfl_xor(mx, 8));
      float mn = fmaxf(m_r[r], mx);
      float al = exp2f((m_r[r] - mn) * cexp);
      m_r[r] = mn;
      float rs = 0.f;
#pragma unroll
      for (int ns = 0; ns < 4; ns++) {
        float p = exp2f((s[ns][r] - mn) * cexp);
        s[ns][r] = p;
        rs += p;
      }
      rs += __shfl_xor(rs, 1);
      rs += __shfl_xor(rs, 2);
      rs += __shfl_xor(rs, 4);
      rs += __shfl_xor(rs, 8);
      l_r[r] = l_r[r] * al + rs;
      alpha[r] = al;
    }

#pragma unroll
    for (int dt = 0; dt < 8; dt++)
#pragma unroll
      for (int r = 0; r < 4; r++) oacc[dt][r] *= alpha[r];

    // ---- P -> per-wave LDS, read back as A-frags (K-dim 64) ----
    unsigned short* pw = &Ps[w * 1152];
#pragma unroll
    for (int r = 0; r < 4; r++) {
      int q = quad * 4 + r;
#pragma unroll
      for (int ns = 0; ns < 4; ns++)
        pw[q * 72 + ns * 16 + l15] = f2bf(s[ns][r]);
    }
    bf16x8 pa0 = *(const bf16x8*)&pw[l15 * 72 + quad * 8];
    bf16x8 pa1 = *(const bf16x8*)&pw[l15 * 72 + 32 + quad * 8];

    // ---- PV: 16 MFMA ----
#pragma unroll
    for (int dt = 0; dt < 8; dt++) {
      bf16x8 vb0 = *(const bf16x8*)&Vs[(dt * 16 + l15) * 72 + quad * 8];
      bf16x8 vb1 = *(const bf16x8*)&Vs[(dt * 16 + l15) * 72 + 32 + quad * 8];
      oacc[dt] = __builtin_amdgcn_mfma_f32_16x16x32_bf16(pa0, vb0, oacc[dt], 0, 0, 0);
      oacc[dt] = __builtin_amdgcn_mfma_f32_16x16x32_bf16(pa1, vb1, oacc[dt], 0, 0, 0);
    }
  }

  float inv[4];
#pragma unroll
  for (int r = 0; r < 4; r++) inv[r] = __builtin_amdgcn_rcpf(l_r[r]);
#pragma unroll
  for (int dt = 0; dt < 8; dt++) {
    int dcat = dt * 16 + l15;
    int col = (dcat < 64) ? (h * 64 + dcat) : (512 + h * 64 + dcat - 64);
#pragma unroll
    for (int r = 0; r < 4; r++) {
      int tok = b * kS + wrow0 + quad * 4 + r;
      out[(size_t)tok * 1024 + col] = f2bf(oacc[dt][r] * inv[r]);
    }
  }
}

// ---------------------------------------------------------------------------
// Launcher
// ---------------------------------------------------------------------------
extern "C" void kernel_launch(void* const* d_in, const int* in_sizes, int n_in,
                              void* d_out, int out_size, void* d_ws, size_t ws_size,
                              hipStream_t stream) {
  const float* x_real = (const float*)d_in[0];
  const float* x_imag = (const float*)d_in[1];
  const float* ln1_gr = (const float*)d_in[2];
  const float* ln1_gi = (const float*)d_in[3];
  const float* ln1_br = (const float*)d_in[4];
  const float* ln1_bi = (const float*)d_in[5];
  const float* q_lm = (const float*)d_in[6];
  const float* q_ph = (const float*)d_in[7];
  const float* q_bm = (const float*)d_in[8];
  const float* q_bp = (const float*)d_in[9];
  const float* k_lm = (const float*)d_in[10];
  const float* k_ph = (const float*)d_in[11];
  const float* k_bm = (const float*)d_in[12];
  const float* k_bp = (const float*)d_in[13];
  const float* v_lm = (const float*)d_in[14];
  const float* v_ph = (const float*)d_in[15];
  const float* v_bm = (const float*)d_in[16];
  const float* v_bp = (const float*)d_in[17];
  const float* o_lm = (const float*)d_in[18];
  const float* o_ph = (const float*)d_in[19];
  const float* o_bm = (const float*)d_in[20];
  const float* o_bp = (const float*)d_in[21];
  const float* ln2_gr = (const float*)d_in[22];
  const float* ln2_gi = (const float*)d_in[23];
  const float* ln2_br = (const float*)d_in[24];
  const float* ln2_bi = (const float*)d_in[25];
  const float* gate_lm = (const float*)d_in[26];
  const float* gate_ph = (const float*)d_in[27];
  const float* up_lm = (const float*)d_in[28];
  const float* up_ph = (const float*)d_in[29];
  const float* down_lm = (const float*)d_in[30];
  const float* down_ph = (const float*)d_in[31];

  // ---- workspace layout (bytes) ----
  char* wsb = (char*)d_ws;
  unsigned short* Wqkv = (unsigned short*)(wsb + 0);           // 3072x1024 bf16
  unsigned short* Wo   = (unsigned short*)(wsb + 6291456);     // 1024x1024
  unsigned short* Wgu  = (unsigned short*)(wsb + 8388608);     // 8192x1024 (role-in-j)
  unsigned short* Wd   = (unsigned short*)(wsb + 25165824);    // 1024x4096 (interleaved K)
  float* qkvBias = (float*)(wsb + 33554432);                   // 3072 fp32
  float* oBias   = (float*)(wsb + 33566720);                   // 1024 fp32
  float* res     = (float*)(wsb + 33570816);                   // 4096x1024 fp32
  unsigned short* H = (unsigned short*)(wsb + 50348032);       // 4096x1024 bf16
  char* big = wsb + 58736640;
  unsigned short* qkv     = (unsigned short*)big;              // 4096x3072 bf16
  unsigned short* attnout = (unsigned short*)(big + 25165824); // 4096x1024 bf16
  unsigned short* vtb     = (unsigned short*)(big + 33554432); // 4x8x128x1024 bf16
  unsigned short* hid     = (unsigned short*)big;              // 4096x4096 bf16 (aliases dead bufs)

  float* outf = (float*)d_out;  // (2, 4096, 512)

  // 1) fused builds (wA includes biases)
  build_wA_kernel<<<4104, 256, 0, stream>>>(q_lm, q_ph, k_lm, k_ph, v_lm, v_ph,
                                            o_lm, o_ph, q_bm, q_bp, k_bm, k_bp,
                                            v_bm, v_bp, o_bm, o_bp,
                                            Wqkv, Wo, qkvBias, oBias);
  build_wB_kernel<<<12288, 256, 0, stream>>>(gate_lm, gate_ph, up_lm, up_ph,
                                             down_lm, down_ph, Wgu, Wd);

  // 2) LN1: x -> H
  cln_kernel<<<kNT / 4, 256, 0, stream>>>(x_real, x_imag, 512, ln1_gr, ln1_gi, ln1_br, ln1_bi, H);

  // 3) QKV fused GEMM (mode 3): rope fused for q/k, V transposed to vtb
  {
    dim3 g(3072 / 128, kNT / 128);
    cgemm_mfma_kernel<<<g, 256, 0, stream>>>(H, 1024, Wqkv, 1024, qkvBias, 3, qkv, 3072, vtb);
  }

  // 4) attention -> attnout
  attn_mfma_kernel<<<kB * kH * (kS / 64), 256, 0, stream>>>(qkv, vtb, attnout);

  // 5) O-proj + x residual -> res fp32
  {
    dim3 g(1024 / 128, kNT / 64);
    cgemm_mfma_n64_kernel<<<g, 256, 0, stream>>>(attnout, 1024, Wo, 1024, oBias, 1,
                                                 x_real, x_imag, res);
  }

  // 6) LN2: res -> H
  cln_kernel<<<kNT / 4, 256, 0, stream>>>(res, res + 512, 1024, ln2_gr, ln2_gi, ln2_br, ln2_bi, H);

  // 7) gate+up GEMM with per-lane fused gating (mode 4) -> hid (N,4096)
  {
    dim3 g(8192 / 128, kNT / 128);
    cgemm_mfma_kernel<<<g, 256, 0, stream>>>(H, 1024, Wgu, 1024, nullptr, 4, hid, 4096, nullptr);
  }

  // 8) down GEMM + residual -> d_out
  {
    dim3 g(1024 / 128, kNT / 64);
    cgemm_mfma_n64_kernel<<<g, 256, 0, stream>>>(hid, 4096, Wd, 4096, nullptr, 2,
                                                 res, nullptr, outf);
  }
}

// Round 8
// 408.866 us; speedup vs baseline: 1.4559x; 1.0602x over previous
//
#include <hip/hip_runtime.h>
#include <math.h>

// Problem constants: B=4, S=1024, D=512, H=8, HD=64, HID=2048
#define kB 4
#define kS 1024
#define kD 512
#define kH 8
#define kHD 64
#define kHID 2048
#define kNT (kB * kS)          // 4096 tokens
#define kBSD (kNT * kD)        // 2,097,152

typedef __attribute__((ext_vector_type(8))) short bf16x8;
typedef __attribute__((ext_vector_type(4))) float f32x4;

#define AS1 __attribute__((address_space(1)))
#define AS3 __attribute__((address_space(3)))

__device__ __forceinline__ float bf2f(unsigned short u) {
  return __uint_as_float(((unsigned int)u) << 16);
}
__device__ __forceinline__ unsigned short f2bf(float f) {
  unsigned int u = __float_as_uint(f);
  u += 0x7fffu + ((u >> 16) & 1u);   // RNE
  return (unsigned short)(u >> 16);
}
__device__ __forceinline__ unsigned int pack2(unsigned short a, unsigned short b) {
  return (unsigned)a | ((unsigned)b << 16);
}

// ---------------------------------------------------------------------------
// Fused build A: QKV (head-permuted) + O (standard cat) + biases + LN1.
// grid 5128 x 256:
//   blocks [0,4096):    weights, seg = gid>>18: 0=q,1=k,2=v (perm), 3=o (std)
//   blocks [4096,4104): biases (2048 threads over 4 segments)
//   blocks [4104,5128): LN1 (one wave per token, 4 tokens/block)
// ---------------------------------------------------------------------------
__global__ __launch_bounds__(256) void build_wA_kernel(
    const float* __restrict__ qlm, const float* __restrict__ qph,
    const float* __restrict__ klm, const float* __restrict__ kph,
    const float* __restrict__ vlm, const float* __restrict__ vph,
    const float* __restrict__ olm, const float* __restrict__ oph,
    const float* __restrict__ qbm, const float* __restrict__ qbp,
    const float* __restrict__ kbm, const float* __restrict__ kbp,
    const float* __restrict__ vbm, const float* __restrict__ vbp,
    const float* __restrict__ obm, const float* __restrict__ obp,
    const float* __restrict__ xr, const float* __restrict__ xi,
    const float* __restrict__ g_r, const float* __restrict__ g_i,
    const float* __restrict__ b_r, const float* __restrict__ b_i,
    unsigned short* __restrict__ Wqkv, unsigned short* __restrict__ Wo,
    float* __restrict__ qkvBias, float* __restrict__ oBias,
    unsigned short* __restrict__ H) {
  int bx = blockIdx.x;
  if (bx >= 4104) {
    // ---- LN1: one wave per token ----
    int w = threadIdx.x >> 6, lane = threadIdx.x & 63;
    int t = (bx - 4104) * 4 + w;
    int d0 = lane * 8;
    const float* xrt = xr + (size_t)t * 512 + d0;
    const float* xit = xi + (size_t)t * 512 + d0;
    float4 a0 = *(const float4*)&xrt[0];
    float4 a1 = *(const float4*)&xrt[4];
    float4 c0 = *(const float4*)&xit[0];
    float4 c1 = *(const float4*)&xit[4];
    float s1 = a0.x + a0.y + a0.z + a0.w + a1.x + a1.y + a1.z + a1.w;
    float s2 = c0.x + c0.y + c0.z + c0.w + c1.x + c1.y + c1.z + c1.w;
#pragma unroll
    for (int off = 1; off < 64; off <<= 1) {
      s1 += __shfl_xor(s1, off);
      s2 += __shfl_xor(s2, off);
    }
    float mr = s1 * (1.f / kD), mi = s2 * (1.f / kD);
    float ar[8] = {a0.x, a0.y, a0.z, a0.w, a1.x, a1.y, a1.z, a1.w};
    float ai[8] = {c0.x, c0.y, c0.z, c0.w, c1.x, c1.y, c1.z, c1.w};
    float v = 0.f;
#pragma unroll
    for (int e = 0; e < 8; e++) {
      float cr = ar[e] - mr, ci = ai[e] - mi;
      v += cr * cr + ci * ci;
    }
#pragma unroll
    for (int off = 1; off < 64; off <<= 1) v += __shfl_xor(v, off);
    float inv = rsqrtf(v * (1.f / kD) + 1e-6f);
    unsigned short pr[8], pi[8];
#pragma unroll
    for (int e = 0; e < 8; e++) {
      float nr = (ar[e] - mr) * inv;
      float ni = (ai[e] - mi) * inv;
      pr[e] = f2bf(nr * g_r[d0 + e] - ni * g_i[d0 + e] + b_r[d0 + e]);
      pi[e] = f2bf(nr * g_i[d0 + e] + ni * g_r[d0 + e] + b_i[d0 + e]);
    }
    unsigned short* ot = H + (size_t)t * 1024 + d0;
    *(bf16x8*)&ot[0] = *(const bf16x8*)pr;
    *(bf16x8*)&ot[512] = *(const bf16x8*)pi;
    return;
  }
  if (bx >= 4096) {
    int gid = (bx - 4096) * 256 + threadIdx.x;  // 0..2047
    int seg = gid >> 9, m = gid & 511;
    const float* bm = seg == 0 ? qbm : seg == 1 ? kbm : seg == 2 ? vbm : obm;
    const float* bp = seg == 0 ? qbp : seg == 1 ? kbp : seg == 2 ? vbp : obp;
    float s, c;
    __sincosf(bp[m], &s, &c);
    float br = bm[m] * c, bi = bm[m] * s;
    if (seg < 3) {
      int h = m >> 6, d = m & 63;
      qkvBias[seg * 1024 + h * 128 + d] = br;
      qkvBias[seg * 1024 + h * 128 + 64 + d] = bi;
    } else {
      oBias[m] = br;
      oBias[512 + m] = bi;
    }
    return;
  }
  int gid = bx * 256 + threadIdx.x;
  int seg = gid >> 18;
  int id = gid & 262143;
  const float* lm = seg == 0 ? qlm : seg == 1 ? klm : seg == 2 ? vlm : olm;
  const float* ph = seg == 0 ? qph : seg == 1 ? kph : seg == 2 ? vph : oph;
  float mm = __expf(lm[id]);
  float s, c;
  __sincosf(ph[id], &s, &c);
  float wr = mm * c, wi = mm * s;
  int m = id >> 9, k = id & 511;
  if (seg < 3) {
    int h = m >> 6, d = m & 63;
    size_t rowR = (size_t)seg * 1024 + h * 128 + d;
    size_t rowI = rowR + 64;
    Wqkv[rowR * 1024 + k] = f2bf(wr);
    Wqkv[rowR * 1024 + 512 + k] = f2bf(-wi);
    Wqkv[rowI * 1024 + k] = f2bf(wi);
    Wqkv[rowI * 1024 + 512 + k] = f2bf(wr);
  } else {
    Wo[(size_t)m * 1024 + k] = f2bf(wr);
    Wo[(size_t)m * 1024 + 512 + k] = f2bf(-wi);
    Wo[(size_t)(512 + m) * 1024 + k] = f2bf(wi);
    Wo[(size_t)(512 + m) * 1024 + 512 + k] = f2bf(wr);
  }
}

// ---------------------------------------------------------------------------
// Fused build B, 2 elements/thread, packed stores. grid 6144 x 256.
// seg = gid>>19: 0=gate,1=up,2=down.
// Wgu role-in-j: feature T -> row (T>>4)*64 + role*16 + (T&15).
// Wd: K interleaved (hr,hi) pairs.
// ---------------------------------------------------------------------------
__global__ __launch_bounds__(256) void build_wB_kernel(
    const float* __restrict__ glm, const float* __restrict__ gph,
    const float* __restrict__ ulm, const float* __restrict__ uph,
    const float* __restrict__ dlm, const float* __restrict__ dph,
    unsigned short* __restrict__ Wgu, unsigned short* __restrict__ Wd) {
  int gid = blockIdx.x * 256 + threadIdx.x;
  int seg = gid >> 19;
  int id0 = (gid & 524287) * 2;
  const float* lm = seg == 0 ? glm : seg == 1 ? ulm : dlm;
  const float* ph = seg == 0 ? gph : seg == 1 ? uph : dph;
  float2 lm2 = *(const float2*)&lm[id0];
  float2 ph2 = *(const float2*)&ph[id0];
  float m0 = __expf(lm2.x), m1 = __expf(lm2.y);
  float s0, c0, s1, c1;
  __sincosf(ph2.x, &s0, &c0);
  __sincosf(ph2.y, &s1, &c1);
  float wr0 = m0 * c0, wi0 = m0 * s0;
  float wr1 = m1 * c1, wi1 = m1 * s1;
  if (seg < 2) {
    int T = id0 >> 9, k = id0 & 511;
    size_t base = (size_t)(T >> 4) * 64 + (T & 15);
    size_t rR = base + (seg * 2 + 0) * 16;
    size_t rI = base + (seg * 2 + 1) * 16;
    *(unsigned int*)&Wgu[rR * 1024 + k] = pack2(f2bf(wr0), f2bf(wr1));
    *(unsigned int*)&Wgu[rR * 1024 + 512 + k] = pack2(f2bf(-wi0), f2bf(-wi1));
    *(unsigned int*)&Wgu[rI * 1024 + k] = pack2(f2bf(wi0), f2bf(wi1));
    *(unsigned int*)&Wgu[rI * 1024 + 512 + k] = pack2(f2bf(wr0), f2bf(wr1));
  } else {
    int m = id0 >> 11, j = id0 & 2047;
    ushort4 a;
    a.x = f2bf(wr0); a.y = f2bf(-wi0); a.z = f2bf(wr1); a.w = f2bf(-wi1);
    *(ushort4*)&Wd[(size_t)m * 4096 + 2 * j] = a;
    ushort4 b;
    b.x = f2bf(wi0); b.y = f2bf(wr0); b.z = f2bf(wi1); b.w = f2bf(wr1);
    *(ushort4*)&Wd[(size_t)(512 + m) * 4096 + 2 * j] = b;
  }
}

// ---------------------------------------------------------------------------
// Complex LayerNorm (LN2): one WAVE per token. fp32 in -> bf16 (N,1024).
// ---------------------------------------------------------------------------
__global__ __launch_bounds__(256) void cln_kernel(
    const float* __restrict__ xr, const float* __restrict__ xi, int stride,
    const float* __restrict__ g_r, const float* __restrict__ g_i,
    const float* __restrict__ b_r, const float* __restrict__ b_i,
    unsigned short* __restrict__ out) {
  int w = threadIdx.x >> 6, lane = threadIdx.x & 63;
  int t = blockIdx.x * 4 + w;
  int d0 = lane * 8;
  const float* xrt = xr + (size_t)t * stride + d0;
  const float* xit = xi + (size_t)t * stride + d0;
  float4 a0 = *(const float4*)&xrt[0];
  float4 a1 = *(const float4*)&xrt[4];
  float4 c0 = *(const float4*)&xit[0];
  float4 c1 = *(const float4*)&xit[4];

  float s1 = a0.x + a0.y + a0.z + a0.w + a1.x + a1.y + a1.z + a1.w;
  float s2 = c0.x + c0.y + c0.z + c0.w + c1.x + c1.y + c1.z + c1.w;
#pragma unroll
  for (int off = 1; off < 64; off <<= 1) {
    s1 += __shfl_xor(s1, off);
    s2 += __shfl_xor(s2, off);
  }
  float mr = s1 * (1.f / kD), mi = s2 * (1.f / kD);

  float ar[8] = {a0.x, a0.y, a0.z, a0.w, a1.x, a1.y, a1.z, a1.w};
  float ai[8] = {c0.x, c0.y, c0.z, c0.w, c1.x, c1.y, c1.z, c1.w};
  float v = 0.f;
#pragma unroll
  for (int e = 0; e < 8; e++) {
    float cr = ar[e] - mr, ci = ai[e] - mi;
    v += cr * cr + ci * ci;
  }
#pragma unroll
  for (int off = 1; off < 64; off <<= 1) v += __shfl_xor(v, off);
  float inv = rsqrtf(v * (1.f / kD) + 1e-6f);

  unsigned short pr[8], pi[8];
#pragma unroll
  for (int e = 0; e < 8; e++) {
    float nr = (ar[e] - mr) * inv;
    float ni = (ai[e] - mi) * inv;
    pr[e] = f2bf(nr * g_r[d0 + e] - ni * g_i[d0 + e] + b_r[d0 + e]);
    pi[e] = f2bf(nr * g_i[d0 + e] + ni * g_r[d0 + e] + b_i[d0 + e]);
  }
  unsigned short* ot = out + (size_t)t * 1024 + d0;
  *(bf16x8*)&ot[0] = *(const bf16x8*)pr;
  *(bf16x8*)&ot[512] = *(const bf16x8*)pi;
}

// ---------------------------------------------------------------------------
// bf16 MFMA GEMM, 128x128 tile, BK=64, 4 waves (unchanged from R7).
// Epilogue modes: 3 = QKV (rope fused, V transposed), 4 = gateup (gating).
// ---------------------------------------------------------------------------
__global__ __launch_bounds__(256) void cgemm_mfma_kernel(
    const unsigned short* __restrict__ X, int ldx,
    const unsigned short* __restrict__ Wt, int K,
    const float* __restrict__ bias, int mode,
    unsigned short* __restrict__ outb, int ldo,
    unsigned short* __restrict__ vtb) {
  __shared__ unsigned short Sh[128 * 64 * 2];   // Xs | Ws, 32 KB
  unsigned short* Xs = Sh;
  unsigned short* Ws = Sh + 8192;

  const int tid = threadIdx.x;
  const int w = tid >> 6;
  const int lane = tid & 63;
  const int quad = lane >> 4;
  const int l15 = lane & 15;
  const int m0 = blockIdx.x * 128;
  const int n0 = blockIdx.y * 128;
  const int wm = (w & 1) * 64;
  const int wn = (w >> 1) * 64;

  const int rsub = lane >> 3;                    // 0..7
  const int grow = w * 32 + rsub;                // + t*8 per inst
  const int gcol = ((lane & 7) ^ rsub) * 8;      // swizzled global granule
  const unsigned short* gx = X + (size_t)(n0 + grow) * ldx + gcol;
  const unsigned short* gw = Wt + (size_t)(m0 + grow) * K + gcol;

  const int rg = (l15 & 7);                      // read-side swizzle key

  f32x4 acc[4][4];
#pragma unroll
  for (int i = 0; i < 4; i++)
#pragma unroll
    for (int j = 0; j < 4; j++) acc[i][j] = (f32x4){0.f, 0.f, 0.f, 0.f};

  for (int k0 = 0; k0 < K; k0 += 64) {
    __syncthreads();
#pragma unroll
    for (int t = 0; t < 4; t++) {
      __builtin_amdgcn_global_load_lds((const AS1 void*)(gx + (size_t)t * 8 * ldx + k0),
                                       (AS3 void*)&Xs[w * 2048 + t * 512], 16, 0, 0);
      __builtin_amdgcn_global_load_lds((const AS1 void*)(gw + (size_t)t * 8 * K + k0),
                                       (AS3 void*)&Ws[w * 2048 + t * 512], 16, 0, 0);
    }
    __syncthreads();

#pragma unroll
    for (int ks = 0; ks < 2; ks++) {
      const int gsel = ((ks * 4 + quad) ^ rg) * 8;
      bf16x8 af[4], bf[4];
#pragma unroll
      for (int t = 0; t < 4; t++) {
        af[t] = *(const bf16x8*)&Xs[(wn + t * 16 + l15) * 64 + gsel];
        bf[t] = *(const bf16x8*)&Ws[(wm + t * 16 + l15) * 64 + gsel];
      }
#pragma unroll
      for (int i = 0; i < 4; i++)
#pragma unroll
        for (int j = 0; j < 4; j++)
          acc[i][j] = __builtin_amdgcn_mfma_f32_16x16x32_bf16(af[i], bf[j], acc[i][j], 0, 0, 0);
    }
  }

  // ---- epilogue; D mapping: col=lane&15 (feature), row=(lane>>4)*4+reg ----
  if (mode == 4) {
    int T = ((m0 + wm) >> 6) * 16 + l15;
#pragma unroll
    for (int i = 0; i < 4; ++i) {
      int row0 = n0 + wn + i * 16 + quad * 4;
#pragma unroll
      for (int r = 0; r < 4; ++r) {
        float gr = acc[i][0][r], gi = acc[i][1][r];
        float ur = acc[i][2][r], ui = acc[i][3][r];
        float sg = __builtin_amdgcn_rcpf(1.f + __expf(-sqrtf(gr * gr + gi * gi)));
        float gar = gr * sg, gai = gi * sg;
        unsigned int pk = pack2(f2bf(gar * ur - gai * ui), f2bf(gar * ui + gai * ur));
        *(unsigned int*)&outb[(size_t)(row0 + r) * ldo + 2 * T] = pk;
      }
    }
  } else if (mode == 3 && m0 < 2048) {
    // q/k: bias + fused RoPE (angle-addition)
#pragma unroll
    for (int j = 0; j < 4; ++j) {
      float bv = bias[m0 + wm + j * 16 + l15];
#pragma unroll
      for (int i = 0; i < 4; ++i)
#pragma unroll
        for (int r = 0; r < 4; ++r) acc[i][j][r] += bv;
    }
    const int sbase = ((n0 + wn) & (kS - 1)) + quad * 4;
#pragma unroll
    for (int j01 = 0; j01 < 2; ++j01) {
      float fi = (float)(j01 * 16 + l15);
      float f = __expf(fi * -0.28782313662425572f);  // -ln(10000)/32
      float c1, s1, c16, s16, cI, sI;
      __sincosf(f, &s1, &c1);
      __sincosf(16.f * f, &s16, &c16);
      __sincosf((float)sbase * f, &sI, &cI);
#pragma unroll
      for (int i = 0; i < 4; ++i) {
        float cc = cI, ss = sI;
#pragma unroll
        for (int r = 0; r < 4; ++r) {
          float x0 = acc[i][j01][r], x1 = acc[i][j01 + 2][r];
          acc[i][j01][r] = x0 * cc - x1 * ss;
          acc[i][j01 + 2][r] = x1 * cc + x0 * ss;
          float cn = cc * c1 - ss * s1;
          ss = ss * c1 + cc * s1;
          cc = cn;
        }
        float cn = cI * c16 - sI * s16;
        sI = sI * c16 + cI * s16;
        cI = cn;
      }
    }
#pragma unroll
    for (int j = 0; j < 4; ++j) {
      int col = m0 + wm + j * 16 + l15;
#pragma unroll
      for (int i = 0; i < 4; ++i) {
        int row0 = n0 + wn + i * 16 + quad * 4;
#pragma unroll
        for (int r = 0; r < 4; ++r)
          outb[(size_t)(row0 + r) * ldo + col] = f2bf(acc[i][j][r]);
      }
    }
  } else {
    // V: LDS-staged transpose, two wave-parity passes. Ts = 64 x 130 shorts.
    unsigned short* Ts = Sh;
#pragma unroll
    for (int p = 0; p < 2; ++p) {
      __syncthreads();
      if ((w & 1) == p) {
#pragma unroll
        for (int j = 0; j < 4; ++j) {
          float bv = bias[m0 + wm + j * 16 + l15];
          int fl = j * 16 + l15;
#pragma unroll
          for (int i = 0; i < 4; ++i) {
            int tk = wn + i * 16 + quad * 4;
#pragma unroll
            for (int r = 0; r < 4; ++r)
              Ts[fl * 130 + tk + r] = f2bf(acc[i][j][r] + bv);
          }
        }
      }
      __syncthreads();
      {
        int fr = tid >> 2, seg = tid & 3;
        int f = (m0 - 2048) + p * 64 + fr;
        int hh = f >> 7, dc = f & 127;
        int bb = n0 >> 10, sbase2 = (n0 & (kS - 1)) + seg * 32;
        unsigned short* dst = &vtb[(size_t)((bb * 8 + hh) * 128 + dc) * 1024 + sbase2];
        const unsigned short* src = &Ts[fr * 130 + seg * 32];
#pragma unroll
        for (int u = 0; u < 4; u++)
          *(bf16x8*)(dst + u * 8) = *(const bf16x8*)(src + u * 8);
      }
    }
  }
}

// ---------------------------------------------------------------------------
// bf16 MFMA GEMM, 64x128 tile, BK=128 (halved barrier count), 4 waves.
// LDS rows 256 B -> 16-granule XOR swizzle (key = row & 15).
// fp32 epilogues: 1 = O-proj (+bias +x residual), 2 = down (+res -> d_out).
// LDS: Xs 64x128 + Ws 128x128 shorts = 48 KB.
// ---------------------------------------------------------------------------
__global__ __launch_bounds__(256) void cgemm_mfma_n64_kernel(
    const unsigned short* __restrict__ X, int ldx,
    const unsigned short* __restrict__ Wt, int K,
    const float* __restrict__ bias, int mode,
    const float* __restrict__ resr, const float* __restrict__ resi,
    float* __restrict__ outf) {
  __shared__ unsigned short Xs[64 * 128];
  __shared__ unsigned short Ws[128 * 128];

  const int tid = threadIdx.x;
  const int w = tid >> 6;
  const int lane = tid & 63;
  const int quad = lane >> 4;
  const int l15 = lane & 15;
  const int m0 = blockIdx.x * 128;
  const int n0 = blockIdx.y * 64;
  const int wm = (w & 1) * 64;
  const int wn = (w >> 1) * 32;

  f32x4 acc[2][4];
#pragma unroll
  for (int i = 0; i < 2; i++)
#pragma unroll
    for (int j = 0; j < 4; j++) acc[i][j] = (f32x4){0.f, 0.f, 0.f, 0.f};

  for (int k0 = 0; k0 < K; k0 += 128) {
    __syncthreads();
    // X staging: 64 rows x 16 chunks; wave w rows [w*16, w*16+16), 4 insts
#pragma unroll
    for (int t = 0; t < 4; t++) {
      int key = t * 4 + quad;            // row & 15 (w*16 drops out)
      int gc = (l15 ^ key) * 8;
      __builtin_amdgcn_global_load_lds(
          (const AS1 void*)(X + (size_t)(n0 + w * 16 + t * 4 + quad) * ldx + k0 + gc),
          (AS3 void*)&Xs[w * 2048 + t * 512], 16, 0, 0);
    }
    // W staging: 128 rows x 16 chunks; wave w rows [w*32, w*32+32), 8 insts
#pragma unroll
    for (int t = 0; t < 8; t++) {
      int key = (t * 4 + quad) & 15;     // row & 15 (w*32 drops out)
      int gc = (l15 ^ key) * 8;
      __builtin_amdgcn_global_load_lds(
          (const AS1 void*)(Wt + (size_t)(m0 + w * 32 + t * 4 + quad) * K + k0 + gc),
          (AS3 void*)&Ws[w * 4096 + t * 512], 16, 0, 0);
    }
    __syncthreads();

#pragma unroll
    for (int ks = 0; ks < 4; ks++) {
      const int gsel = ((ks * 4 + quad) ^ l15) * 8;   // key = row&15 = l15
      bf16x8 af[2], bf[4];
#pragma unroll
      for (int t = 0; t < 2; t++)
        af[t] = *(const bf16x8*)&Xs[(wn + t * 16 + l15) * 128 + gsel];
#pragma unroll
      for (int t = 0; t < 4; t++)
        bf[t] = *(const bf16x8*)&Ws[(wm + t * 16 + l15) * 128 + gsel];
#pragma unroll
      for (int i = 0; i < 2; i++)
#pragma unroll
        for (int j = 0; j < 4; j++)
          acc[i][j] = __builtin_amdgcn_mfma_f32_16x16x32_bf16(af[i], bf[j], acc[i][j], 0, 0, 0);
    }
  }

#pragma unroll
  for (int j = 0; j < 4; ++j) {
    int col = m0 + wm + j * 16 + l15;
    float bv = bias ? bias[col] : 0.f;
#pragma unroll
    for (int i = 0; i < 2; ++i) {
      int row0 = n0 + wn + i * 16 + quad * 4;
#pragma unroll
      for (int r = 0; r < 4; ++r) {
        int row = row0 + r;
        float val = acc[i][j][r] + bv;
        if (mode == 1) {
          float xres = (col < 512) ? resr[(size_t)row * 512 + col]
                                   : resi[(size_t)row * 512 + col - 512];
          outf[(size_t)row * 1024 + col] = val + xres;
        } else {
          float rv = resr[(size_t)row * 1024 + col] + val;
          size_t dd = (col < 512) ? ((size_t)row * 512 + col)
                                  : ((size_t)kBSD + (size_t)row * 512 + (col - 512));
          outf[dd] = rv;
        }
      }
    }
  }
}

// ---------------------------------------------------------------------------
// MFMA flash attention (causal, Hermitian). K-tile = 64.
// Block decode gives complementary qt to bid and bid+256 so each CU's two
// blocks sum to a uniform 17 K-iterations (load balance).
// LDS: Ks 64x136 + Vs 128x72 + Ps 4x16x72 = 45,056 B.
// ---------------------------------------------------------------------------
__global__ __launch_bounds__(256) void attn_mfma_kernel(
    const unsigned short* __restrict__ qkv,   // (4096, 3072)
    const unsigned short* __restrict__ vt,    // (4,8,128,1024)
    unsigned short* __restrict__ out) {       // (4096, 1024) [ar|ai]
  __shared__ unsigned short Ks[64 * 136];
  __shared__ unsigned short Vs[128 * 72];
  __shared__ unsigned short Ps[4 * 16 * 72];

  const int tid = threadIdx.x;
  const int w = tid >> 6;
  const int lane = tid & 63;
  const int quad = lane >> 4;
  const int l15 = lane & 15;

  int bid = blockIdx.x;
  int second = bid >> 8;             // 0: blocks 0..255, 1: 256..511
  int u = bid & 255;
  int t_ = u & 15;
  const int qt = second ? (15 - t_) : t_;   // complementary across halves
  const int h = (u >> 4) & 7;
  const int b = second * 2 + (u >> 7);
  const int q0 = qt * 64;
  const int wrow0 = q0 + w * 16;

  bf16x8 qa[4];
  {
    size_t base = (size_t)(b * kS + wrow0 + l15) * 3072 + h * 128;
#pragma unroll
    for (int ks = 0; ks < 4; ks++)
      qa[ks] = *(const bf16x8*)&qkv[base + ks * 32 + quad * 8];
  }

  f32x4 oacc[8];
#pragma unroll
  for (int dt = 0; dt < 8; dt++) oacc[dt] = (f32x4){0.f, 0.f, 0.f, 0.f};
  float m_r[4] = {-1e30f, -1e30f, -1e30f, -1e30f};
  float l_r[4] = {0.f, 0.f, 0.f, 0.f};

  const int nkt = qt + 1;
  const float cexp = 0.1803368801f;  // (1/sqrt(64)) * log2(e)

  const unsigned short* gkbase = qkv + 1024 + h * 128;
  const unsigned short* gvbase = vt + (size_t)((b * 8 + h) * 128) * 1024;

  for (int kt = 0; kt < nkt; ++kt) {
    const int k0 = kt * 64;
    __syncthreads();
    {
      const unsigned short* gk = gkbase + (size_t)(b * kS + k0) * 3072;
      int ch = tid * 4;
#pragma unroll
      for (int u2 = 0; u2 < 4; u2++) {
        int r = (ch + u2) >> 4, cc = ((ch + u2) & 15) * 8;
        *(bf16x8*)&Ks[r * 136 + cc] = *(const bf16x8*)&gk[(size_t)r * 3072 + cc];
      }
#pragma unroll
      for (int u2 = 0; u2 < 4; u2++) {
        int vr = (ch + u2) >> 3, vc = ((ch + u2) & 7) * 8;
        *(bf16x8*)&Vs[vr * 72 + vc] = *(const bf16x8*)&gvbase[(size_t)vr * 1024 + k0 + vc];
      }
    }
    __syncthreads();

    f32x4 s[4];
#pragma unroll
    for (int ns = 0; ns < 4; ns++) {
      s[ns] = (f32x4){0.f, 0.f, 0.f, 0.f};
#pragma unroll
      for (int ks = 0; ks < 4; ks++) {
        bf16x8 kb = *(const bf16x8*)&Ks[(ns * 16 + l15) * 136 + ks * 32 + quad * 8];
        s[ns] = __builtin_amdgcn_mfma_f32_16x16x32_bf16(qa[ks], kb, s[ns], 0, 0, 0);
      }
    }

    if (k0 + 63 > wrow0) {
#pragma unroll
      for (int r = 0; r < 4; r++) {
        int qrow = wrow0 + quad * 4 + r;
#pragma unroll
        for (int ns = 0; ns < 4; ns++)
          if (k0 + ns * 16 + l15 > qrow) s[ns][r] = -1e30f;
      }
    }

    float alpha[4];
#pragma unroll
    for (int r = 0; r < 4; r++) {
      float mx = fmaxf(fmaxf(s[0][r], s[1][r]), fmaxf(s[2][r], s[3][r]));
      mx = fmaxf(mx, __shfl_xor(mx, 1));
      mx = fmaxf(mx, __shfl_xor(mx, 2));
      mx = fmaxf(mx, __shfl_xor(mx, 4));
      mx = fmaxf(mx, __shfl_xor(mx, 8));
      float mn = fmaxf(m_r[r], mx);
      float al = exp2f((m_r[r] - mn) * cexp);
      m_r[r] = mn;
      float rs = 0.f;
#pragma unroll
      for (int ns = 0; ns < 4; ns++) {
        float p = exp2f((s[ns][r] - mn) * cexp);
        s[ns][r] = p;
        rs += p;
      }
      rs += __shfl_xor(rs, 1);
      rs += __shfl_xor(rs, 2);
      rs += __shfl_xor(rs, 4);
      rs += __shfl_xor(rs, 8);
      l_r[r] = l_r[r] * al + rs;
      alpha[r] = al;
    }

#pragma unroll
    for (int dt = 0; dt < 8; dt++)
#pragma unroll
      for (int r = 0; r < 4; r++) oacc[dt][r] *= alpha[r];

    unsigned short* pw = &Ps[w * 1152];
#pragma unroll
    for (int r = 0; r < 4; r++) {
      int q = quad * 4 + r;
#pragma unroll
      for (int ns = 0; ns < 4; ns++)
        pw[q * 72 + ns * 16 + l15] = f2bf(s[ns][r]);
    }
    bf16x8 pa0 = *(const bf16x8*)&pw[l15 * 72 + quad * 8];
    bf16x8 pa1 = *(const bf16x8*)&pw[l15 * 72 + 32 + quad * 8];

#pragma unroll
    for (int dt = 0; dt < 8; dt++) {
      bf16x8 vb0 = *(const bf16x8*)&Vs[(dt * 16 + l15) * 72 + quad * 8];
      bf16x8 vb1 = *(const bf16x8*)&Vs[(dt * 16 + l15) * 72 + 32 + quad * 8];
      oacc[dt] = __builtin_amdgcn_mfma_f32_16x16x32_bf16(pa0, vb0, oacc[dt], 0, 0, 0);
      oacc[dt] = __builtin_amdgcn_mfma_f32_16x16x32_bf16(pa1, vb1, oacc[dt], 0, 0, 0);
    }
  }

  float inv[4];
#pragma unroll
  for (int r = 0; r < 4; r++) inv[r] = __builtin_amdgcn_rcpf(l_r[r]);
#pragma unroll
  for (int dt = 0; dt < 8; dt++) {
    int dcat = dt * 16 + l15;
    int col = (dcat < 64) ? (h * 64 + dcat) : (512 + h * 64 + dcat - 64);
#pragma unroll
    for (int r = 0; r < 4; r++) {
      int tok = b * kS + wrow0 + quad * 4 + r;
      out[(size_t)tok * 1024 + col] = f2bf(oacc[dt][r] * inv[r]);
    }
  }
}

// ---------------------------------------------------------------------------
// Launcher
// ---------------------------------------------------------------------------
extern "C" void kernel_launch(void* const* d_in, const int* in_sizes, int n_in,
                              void* d_out, int out_size, void* d_ws, size_t ws_size,
                              hipStream_t stream) {
  const float* x_real = (const float*)d_in[0];
  const float* x_imag = (const float*)d_in[1];
  const float* ln1_gr = (const float*)d_in[2];
  const float* ln1_gi = (const float*)d_in[3];
  const float* ln1_br = (const float*)d_in[4];
  const float* ln1_bi = (const float*)d_in[5];
  const float* q_lm = (const float*)d_in[6];
  const float* q_ph = (const float*)d_in[7];
  const float* q_bm = (const float*)d_in[8];
  const float* q_bp = (const float*)d_in[9];
  const float* k_lm = (const float*)d_in[10];
  const float* k_ph = (const float*)d_in[11];
  const float* k_bm = (const float*)d_in[12];
  const float* k_bp = (const float*)d_in[13];
  const float* v_lm = (const float*)d_in[14];
  const float* v_ph = (const float*)d_in[15];
  const float* v_bm = (const float*)d_in[16];
  const float* v_bp = (const float*)d_in[17];
  const float* o_lm = (const float*)d_in[18];
  const float* o_ph = (const float*)d_in[19];
  const float* o_bm = (const float*)d_in[20];
  const float* o_bp = (const float*)d_in[21];
  const float* ln2_gr = (const float*)d_in[22];
  const float* ln2_gi = (const float*)d_in[23];
  const float* ln2_br = (const float*)d_in[24];
  const float* ln2_bi = (const float*)d_in[25];
  const float* gate_lm = (const float*)d_in[26];
  const float* gate_ph = (const float*)d_in[27];
  const float* up_lm = (const float*)d_in[28];
  const float* up_ph = (const float*)d_in[29];
  const float* down_lm = (const float*)d_in[30];
  const float* down_ph = (const float*)d_in[31];

  // ---- workspace layout (bytes) ----
  char* wsb = (char*)d_ws;
  unsigned short* Wqkv = (unsigned short*)(wsb + 0);           // 3072x1024 bf16
  unsigned short* Wo   = (unsigned short*)(wsb + 6291456);     // 1024x1024
  unsigned short* Wgu  = (unsigned short*)(wsb + 8388608);     // 8192x1024 (role-in-j)
  unsigned short* Wd   = (unsigned short*)(wsb + 25165824);    // 1024x4096 (interleaved K)
  float* qkvBias = (float*)(wsb + 33554432);                   // 3072 fp32
  float* oBias   = (float*)(wsb + 33566720);                   // 1024 fp32
  float* res     = (float*)(wsb + 33570816);                   // 4096x1024 fp32
  unsigned short* H = (unsigned short*)(wsb + 50348032);       // 4096x1024 bf16
  char* big = wsb + 58736640;
  unsigned short* qkv     = (unsigned short*)big;              // 4096x3072 bf16
  unsigned short* attnout = (unsigned short*)(big + 25165824); // 4096x1024 bf16
  unsigned short* vtb     = (unsigned short*)(big + 33554432); // 4x8x128x1024 bf16
  unsigned short* hid     = (unsigned short*)big;              // 4096x4096 bf16 (aliases dead bufs)

  float* outf = (float*)d_out;  // (2, 4096, 512)

  // 1) fused builds (wA includes biases + LN1)
  build_wA_kernel<<<5128, 256, 0, stream>>>(q_lm, q_ph, k_lm, k_ph, v_lm, v_ph,
                                            o_lm, o_ph, q_bm, q_bp, k_bm, k_bp,
                                            v_bm, v_bp, o_bm, o_bp,
                                            x_real, x_imag, ln1_gr, ln1_gi,
                                            ln1_br, ln1_bi,
                                            Wqkv, Wo, qkvBias, oBias, H);
  build_wB_kernel<<<6144, 256, 0, stream>>>(gate_lm, gate_ph, up_lm, up_ph,
                                            down_lm, down_ph, Wgu, Wd);

  // 2) QKV fused GEMM (mode 3): rope fused for q/k, V transposed to vtb
  {
    dim3 g(3072 / 128, kNT / 128);
    cgemm_mfma_kernel<<<g, 256, 0, stream>>>(H, 1024, Wqkv, 1024, qkvBias, 3, qkv, 3072, vtb);
  }

  // 3) attention -> attnout (load-balanced decode)
  attn_mfma_kernel<<<kB * kH * (kS / 64), 256, 0, stream>>>(qkv, vtb, attnout);

  // 4) O-proj + x residual -> res fp32 (BK=128)
  {
    dim3 g(1024 / 128, kNT / 64);
    cgemm_mfma_n64_kernel<<<g, 256, 0, stream>>>(attnout, 1024, Wo, 1024, oBias, 1,
                                                 x_real, x_imag, res);
  }

  // 5) LN2: res -> H
  cln_kernel<<<kNT / 4, 256, 0, stream>>>(res, res + 512, 1024, ln2_gr, ln2_gi, ln2_br, ln2_bi, H);

  // 6) gate+up GEMM with per-lane fused gating (mode 4) -> hid (N,4096)
  {
    dim3 g(8192 / 128, kNT / 128);
    cgemm_mfma_kernel<<<g, 256, 0, stream>>>(H, 1024, Wgu, 1024, nullptr, 4, hid, 4096, nullptr);
  }

  // 7) down GEMM + residual -> d_out (BK=128)
  {
    dim3 g(1024 / 128, kNT / 64);
    cgemm_mfma_n64_kernel<<<g, 256, 0, stream>>>(hid, 4096, Wd, 4096, nullptr, 2,
                                                 res, nullptr, outf);
  }
}